// Round 5
// baseline (317.804 us; speedup 1.0000x reference)
//
#include <hip/hip_runtime.h>

#define N_NODES 100000
#define N_EDGES 20000
#define NNZ     1600000
#define D       128
#define DW      64                         // uints per bf16 row (2 ch per uint)

#define NB      256                        // buckets per side
#define CAP_E   8192
#define CAP_V   8192
#define SPAN_E  ((N_EDGES + NB - 1) / NB)  // 79
#define SPAN_V  ((N_NODES + NB - 1) / NB)  // 391
#define P1_CHUNK 2048
#define P1_ITER  (P1_CHUNK / 256)          // 8
#define P1_BLOCKS ((NNZ + P1_CHUNK - 1) / P1_CHUNK)  // 782

__device__ __forceinline__ unsigned int pack_bf2(float lo, float hi) {
  unsigned int ul = __float_as_uint(lo), uh = __float_as_uint(hi);
  ul = (ul + 0x7FFFu + ((ul >> 16) & 1u)) >> 16;
  uh = (uh + 0x7FFFu + ((uh >> 16) & 1u)) & 0xFFFF0000u;
  return ul | uh;
}

// ---------------- init bucket cursors ----------------
__global__ void k_init(int* __restrict__ ce, int* __restrict__ cv) {
  int t = threadIdx.x;
  ce[t] = t * CAP_E;
  cv[t] = t * CAP_V;
}

// ---------------- pass 1: bin incidences ----------------
__global__ __launch_bounds__(256) void k_bin(const int* __restrict__ v_idx, const int* __restrict__ e_idx,
                                             int* __restrict__ ce, int* __restrict__ cv,
                                             unsigned int* __restrict__ Te, unsigned int* __restrict__ Tv) {
  __shared__ int he[NB], hv[NB], be[NB], bv[NB], le[NB], lv[NB];
  int t = threadIdx.x;
  he[t] = 0; hv[t] = 0; le[t] = 0; lv[t] = 0;
  __syncthreads();
  int base = blockIdx.x * P1_CHUNK;
  int v[P1_ITER], e[P1_ITER];
#pragma unroll
  for (int j = 0; j < P1_ITER; ++j) {
    int idx = base + j * 256 + t;
    if (idx < NNZ) {
      v[j] = v_idx[idx]; e[j] = e_idx[idx];
      atomicAdd(&he[e[j] / SPAN_E], 1);
      atomicAdd(&hv[v[j] / SPAN_V], 1);
    } else v[j] = -1;
  }
  __syncthreads();
  be[t] = he[t] ? atomicAdd(&ce[t], he[t]) : 0;
  bv[t] = hv[t] ? atomicAdd(&cv[t], hv[t]) : 0;
  __syncthreads();
#pragma unroll
  for (int j = 0; j < P1_ITER; ++j) {
    if (v[j] < 0) continue;
    int eb = e[j] / SPAN_E, vb = v[j] / SPAN_V;
    int se = be[eb] + atomicAdd(&le[eb], 1);
    int sv = bv[vb] + atomicAdd(&lv[vb], 1);
    if (se < (eb + 1) * CAP_E) Te[se] = ((unsigned)e[j] << 17) | (unsigned)v[j];
    if (sv < (vb + 1) * CAP_V) Tv[sv] = ((unsigned)v[j] << 15) | (unsigned)e[j];
  }
}

// ---------------- pass 2 (vertex side) + fused prescale ----------------
__global__ __launch_bounds__(256) void k_sort_v(const int* __restrict__ cv, unsigned int* __restrict__ Tv,
                                                int* __restrict__ cnt_v, float* __restrict__ risv,
                                                int* __restrict__ starts_v,
                                                const float* __restrict__ X, unsigned int* __restrict__ Xs) {
  __shared__ unsigned int raw[CAP_V];
  __shared__ int hist[SPAN_V], lcur[SPAN_V], loff[SPAN_V + 1];
  __shared__ float rv[SPAN_V];
  int b = blockIdx.x, t = threadIdx.x;
  int v0 = b * SPAN_V;
  int span = N_NODES - v0; if (span > SPAN_V) span = SPAN_V;
  if (span <= 0) return;
  int n = cv[b] - b * CAP_V; if (n > CAP_V) n = CAP_V; if (n < 0) n = 0;
  for (int i = t; i < n; i += 256) raw[i] = Tv[b * CAP_V + i];
  for (int i = t; i < span; i += 256) { hist[i] = 0; lcur[i] = 0; }
  __syncthreads();
  for (int i = t; i < n; i += 256) atomicAdd(&hist[(int)(raw[i] >> 15) - v0], 1);
  __syncthreads();
  if (t == 0) { int run = 0; for (int i = 0; i < span; ++i) { loff[i] = run; run += hist[i]; } loff[span] = run; }
  __syncthreads();
  for (int i = t; i < n; i += 256) {
    unsigned int p = raw[i];
    int l = (int)(p >> 15) - v0;
    int slot = loff[l] + atomicAdd(&lcur[l], 1);
    Tv[b * CAP_V + slot] = p & 0x7FFFu;
  }
  for (int i = t; i < span; i += 256) {
    int d = hist[i];
    float r = d > 0 ? rsqrtf((float)d) : 0.0f;
    cnt_v[v0 + i] = d;
    risv[v0 + i] = r;
    rv[i] = r;
    starts_v[v0 + i] = b * CAP_V + loff[i];
  }
  __syncthreads();
  // fused prescale: Xs[v] = bf16(risv[v] * X[v]) for this block's vertex range
  int total = span * DW;
  for (int idx = t; idx < total; idx += 256) {
    int vl = idx >> 6;
    float r = rv[vl];
    size_t gp = (size_t)(v0 + vl) * DW + (idx & 63);
    float2 x = *(const float2*)(X + gp * 2);
    Xs[gp] = pack_bf2(r * x.x, r * x.y);
  }
}

// ---------------- pass 2 (edge side): sort + degrees + qv[e] = sum risv[v] ----------------
__global__ __launch_bounds__(256) void k_sort_e(const int* __restrict__ ce, unsigned int* __restrict__ Te,
                                                const float* __restrict__ risv,
                                                int* __restrict__ cnt_e, float* __restrict__ invde,
                                                int* __restrict__ starts_e, float* __restrict__ qv) {
  __shared__ unsigned int raw[CAP_E];
  __shared__ int hist[SPAN_E], lcur[SPAN_E], loff[SPAN_E + 1];
  __shared__ float qacc[SPAN_E];
  int b = blockIdx.x, t = threadIdx.x;
  int e0 = b * SPAN_E;
  int span = N_EDGES - e0; if (span > SPAN_E) span = SPAN_E;
  if (span <= 0) return;
  int n = ce[b] - b * CAP_E; if (n > CAP_E) n = CAP_E; if (n < 0) n = 0;
  for (int i = t; i < n; i += 256) raw[i] = Te[b * CAP_E + i];
  for (int i = t; i < span; i += 256) { hist[i] = 0; lcur[i] = 0; qacc[i] = 0.f; }
  __syncthreads();
  for (int i = t; i < n; i += 256) atomicAdd(&hist[(int)(raw[i] >> 17) - e0], 1);
  __syncthreads();
  if (t == 0) { int run = 0; for (int i = 0; i < span; ++i) { loff[i] = run; run += hist[i]; } loff[span] = run; }
  __syncthreads();
  for (int i = t; i < n; i += 256) {
    unsigned int p = raw[i];
    int l = (int)(p >> 17) - e0;
    int vtx = (int)(p & 0x1FFFFu);
    int slot = loff[l] + atomicAdd(&lcur[l], 1);
    Te[b * CAP_E + slot] = (unsigned)vtx;
    atomicAdd(&qacc[l], risv[vtx]);
  }
  __syncthreads();
  for (int i = t; i < span; i += 256) {
    int d = hist[i];
    cnt_e[e0 + i] = d;
    invde[e0 + i] = d > 0 ? 1.0f / (float)d : 0.0f;
    starts_e[e0 + i] = b * CAP_E + loff[i];
    qv[e0 + i] = qacc[i];
  }
}

// ---------------- phase A: Qeb[e] = bf16( sum Xs[v] ) ----------------
__global__ void k_edge_gather(const unsigned int* __restrict__ Xs,
                              const int* __restrict__ starts_e, const int* __restrict__ cnt_e,
                              const unsigned int* __restrict__ members,
                              unsigned int* __restrict__ Qeb) {
  int wid = (blockIdx.x * 256 + threadIdx.x) >> 6;   // one wave per edge
  int lane = threadIdx.x & 63;
  if (wid >= N_EDGES) return;
  int beg = __builtin_amdgcn_readfirstlane(starts_e[wid]);
  int end = beg + __builtin_amdgcn_readfirstlane(cnt_e[wid]);
  float ax = 0.f, ay = 0.f;
  int i = beg;
  for (; i + 16 <= end; i += 16) {
    int vv[16]; unsigned int xx[16];
#pragma unroll
    for (int j = 0; j < 16; ++j) vv[j] = members[i + j];
#pragma unroll
    for (int j = 0; j < 16; ++j) xx[j] = Xs[(size_t)vv[j] * DW + lane];
#pragma unroll
    for (int j = 0; j < 16; ++j) {
      ax += __uint_as_float(xx[j] << 16);
      ay += __uint_as_float(xx[j] & 0xFFFF0000u);
    }
  }
  if (i + 8 <= end) {
    int vv[8]; unsigned int xx[8];
#pragma unroll
    for (int j = 0; j < 8; ++j) vv[j] = members[i + j];
#pragma unroll
    for (int j = 0; j < 8; ++j) xx[j] = Xs[(size_t)vv[j] * DW + lane];
#pragma unroll
    for (int j = 0; j < 8; ++j) {
      ax += __uint_as_float(xx[j] << 16);
      ay += __uint_as_float(xx[j] & 0xFFFF0000u);
    }
    i += 8;
  }
  for (; i < end; ++i) {
    unsigned int x = Xs[(size_t)members[i] * DW + lane];
    ax += __uint_as_float(x << 16);
    ay += __uint_as_float(x & 0xFFFF0000u);
  }
  Qeb[(size_t)wid * DW + lane] = pack_bf2(ax, ay);
}

// ---------------- GEMM: Yeb[e] = bf16( invde[e] * (Qeb[e] @ W + qv[e] * b) ) ----------------
__global__ __launch_bounds__(256) void k_gemm(const unsigned int* __restrict__ Qeb, const float* __restrict__ qv,
                                              const float* __restrict__ W, const float* __restrict__ bias,
                                              const float* __restrict__ invde, unsigned int* __restrict__ Yeb) {
  __shared__ float Wl[D * D];
  __shared__ float bl[D];
  __shared__ float Ql[16][130];
  int tid = threadIdx.x;
  const float4* W4 = (const float4*)W;
  float4* Wl4 = (float4*)Wl;
#pragma unroll
  for (int j = 0; j < 16; ++j) Wl4[tid + 256 * j] = W4[tid + 256 * j];
  if (tid < 32) ((float4*)bl)[tid] = ((const float4*)bias)[tid];
  int row0 = blockIdx.x * 16;
  const unsigned int* Q8 = Qeb + (size_t)row0 * DW;
#pragma unroll
  for (int j = 0; j < 4; ++j) {
    int idx = tid + 256 * j;          // 0..1023 (16 rows x 64 uints)
    int r = idx >> 6, c = idx & 63;
    unsigned int u = Q8[idx];
    Ql[r][2 * c]     = __uint_as_float(u << 16);
    Ql[r][2 * c + 1] = __uint_as_float(u & 0xFFFF0000u);
  }
  __syncthreads();
  int ty = tid >> 4, tx = tid & 15;
  float acc[8];
#pragma unroll
  for (int j = 0; j < 8; ++j) acc[j] = 0.f;
#pragma unroll 4
  for (int k = 0; k < D; ++k) {
    float xv = Ql[ty][k];
    const float* wr = Wl + k * D + tx * 8;
#pragma unroll
    for (int j = 0; j < 8; ++j) acc[j] += xv * wr[j];
  }
  int row = row0 + ty;
  float s = invde[row]; float q = qv[row];
  unsigned int* orow = Yeb + (size_t)row * DW + tx * 4;
#pragma unroll
  for (int j = 0; j < 4; ++j) {
    float lo = s * (acc[2 * j]     + q * bl[tx * 8 + 2 * j]);
    float hi = s * (acc[2 * j + 1] + q * bl[tx * 8 + 2 * j + 1]);
    orow[j] = pack_bf2(lo, hi);
  }
}

// ---------------- phase B: out[v] = relu(risv[v] * sum Yeb[e]) ----------------
__global__ void k_vertex_gather(const unsigned int* __restrict__ Yeb, const float* __restrict__ risv,
                                const int* __restrict__ starts_v, const int* __restrict__ cnt_v,
                                const unsigned int* __restrict__ members,
                                float* __restrict__ out) {
  int wid = (blockIdx.x * 256 + threadIdx.x) >> 6;   // one wave per vertex
  int lane = threadIdx.x & 63;
  if (wid >= N_NODES) return;
  int beg = __builtin_amdgcn_readfirstlane(starts_v[wid]);
  int end = beg + __builtin_amdgcn_readfirstlane(cnt_v[wid]);
  float ax = 0.f, ay = 0.f;
  int i = beg;
  for (; i + 16 <= end; i += 16) {
    int ee[16]; unsigned int yy[16];
#pragma unroll
    for (int j = 0; j < 16; ++j) ee[j] = members[i + j];
#pragma unroll
    for (int j = 0; j < 16; ++j) yy[j] = Yeb[(size_t)ee[j] * DW + lane];
#pragma unroll
    for (int j = 0; j < 16; ++j) {
      ax += __uint_as_float(yy[j] << 16);
      ay += __uint_as_float(yy[j] & 0xFFFF0000u);
    }
  }
  if (i + 8 <= end) {
    int ee[8]; unsigned int yy[8];
#pragma unroll
    for (int j = 0; j < 8; ++j) ee[j] = members[i + j];
#pragma unroll
    for (int j = 0; j < 8; ++j) yy[j] = Yeb[(size_t)ee[j] * DW + lane];
#pragma unroll
    for (int j = 0; j < 8; ++j) {
      ax += __uint_as_float(yy[j] << 16);
      ay += __uint_as_float(yy[j] & 0xFFFF0000u);
    }
    i += 8;
  }
  for (; i < end; ++i) {
    unsigned int y = Yeb[(size_t)members[i] * DW + lane];
    ax += __uint_as_float(y << 16);
    ay += __uint_as_float(y & 0xFFFF0000u);
  }
  float s = risv[wid];
  float2 o; o.x = fmaxf(ax * s, 0.f); o.y = fmaxf(ay * s, 0.f);
  *(float2*)(out + (size_t)wid * D + lane * 2) = o;
}

extern "C" void kernel_launch(void* const* d_in, const int* in_sizes, int n_in,
                              void* d_out, int out_size, void* d_ws, size_t ws_size,
                              hipStream_t stream) {
  const float* X    = (const float*)d_in[0];
  const float* W    = (const float*)d_in[1];
  const float* bias = (const float*)d_in[2];
  const int* v_idx  = (const int*)d_in[3];
  const int* e_idx  = (const int*)d_in[4];
  float* out = (float*)d_out;

  char* p = (char*)d_ws;
  auto alloc = [&](size_t bytes) { char* r = p; p += (bytes + 255) & ~(size_t)255; return r; };
  unsigned int* Te  = (unsigned int*)alloc((size_t)NB * CAP_E * 4);
  unsigned int* Tv  = (unsigned int*)alloc((size_t)NB * CAP_V * 4);
  unsigned int* Xs  = (unsigned int*)alloc((size_t)N_NODES * DW * 4);
  unsigned int* Qeb = (unsigned int*)alloc((size_t)N_EDGES * DW * 4);
  unsigned int* Yeb = (unsigned int*)alloc((size_t)N_EDGES * DW * 4);
  float* qv    = (float*)alloc((size_t)N_EDGES * 4);
  float* risv  = (float*)alloc((size_t)N_NODES * 4);
  float* invde = (float*)alloc((size_t)N_EDGES * 4);
  int* cnt_e    = (int*)alloc((size_t)N_EDGES * 4);
  int* cnt_v    = (int*)alloc((size_t)N_NODES * 4);
  int* starts_e = (int*)alloc((size_t)N_EDGES * 4);
  int* starts_v = (int*)alloc((size_t)N_NODES * 4);
  int* ce       = (int*)alloc(NB * 4);
  int* cv       = (int*)alloc(NB * 4);

  k_init<<<1, NB, 0, stream>>>(ce, cv);
  k_bin<<<P1_BLOCKS, 256, 0, stream>>>(v_idx, e_idx, ce, cv, Te, Tv);
  k_sort_v<<<NB, 256, 0, stream>>>(cv, Tv, cnt_v, risv, starts_v, X, Xs);
  k_sort_e<<<NB, 256, 0, stream>>>(ce, Te, risv, cnt_e, invde, starts_e, qv);

  k_edge_gather<<<N_EDGES / 4, 256, 0, stream>>>(Xs, starts_e, cnt_e, Te, Qeb);
  k_gemm<<<N_EDGES / 16, 256, 0, stream>>>(Qeb, qv, W, bias, invde, Yeb);
  k_vertex_gather<<<N_NODES / 4, 256, 0, stream>>>(Yeb, risv, starts_v, cnt_v, Tv, out);
}

// Round 6
// 289.493 us; speedup vs baseline: 1.0978x; 1.0978x over previous
//
#include <hip/hip_runtime.h>

#define N_NODES 100000
#define N_EDGES 20000
#define NNZ     1600000
#define D       128
#define DW      64                         // uints per bf16 row (2 ch per uint)

#define NB      256                        // buckets per side
#define CAP_E   8192
#define CAP_V   8192
#define SPAN_E  ((N_EDGES + NB - 1) / NB)  // 79
#define SPAN_V  ((N_NODES + NB - 1) / NB)  // 391
#define P1_CHUNK 8192
#define P1_ITER  (P1_CHUNK / 256)          // 32
#define P1_BLOCKS ((NNZ + P1_CHUNK - 1) / P1_CHUNK)  // 196

typedef __attribute__((ext_vector_type(8))) short bf16x8;
typedef __attribute__((ext_vector_type(4))) float f32x4;

__device__ __forceinline__ unsigned int pack_bf2(float lo, float hi) {
  unsigned int ul = __float_as_uint(lo), uh = __float_as_uint(hi);
  ul = (ul + 0x7FFFu + ((ul >> 16) & 1u)) >> 16;
  uh = (uh + 0x7FFFu + ((uh >> 16) & 1u)) & 0xFFFF0000u;
  return ul | uh;
}

// ---------------- prep: cursor init + Wtp[c][kp] = bf16pack(W[2kp][c], W[2kp+1][c]) ----------------
__global__ __launch_bounds__(256) void k_prep(const float* __restrict__ W, unsigned int* __restrict__ Wtp,
                                              int* __restrict__ ce, int* __restrict__ cv) {
  int t = threadIdx.x;
  if (blockIdx.x == 0) { ce[t] = t * CAP_E; cv[t] = t * CAP_V; }
  int idx = blockIdx.x * 256 + t;
  if (idx < D * DW) {
    int c = idx & 127, kp = idx >> 7;                 // coalesced W row reads
    float lo = W[(size_t)(2 * kp) * D + c];
    float hi = W[(size_t)(2 * kp + 1) * D + c];
    Wtp[c * DW + kp] = pack_bf2(lo, hi);
  }
}

// ---------------- pass 1: bin incidences ----------------
__global__ __launch_bounds__(256) void k_bin(const int* __restrict__ v_idx, const int* __restrict__ e_idx,
                                             int* __restrict__ ce, int* __restrict__ cv,
                                             unsigned int* __restrict__ Te, unsigned int* __restrict__ Tv) {
  __shared__ int he[NB], hv[NB], be[NB], bv[NB], le[NB], lv[NB];
  int t = threadIdx.x;
  he[t] = 0; hv[t] = 0; le[t] = 0; lv[t] = 0;
  __syncthreads();
  int base = blockIdx.x * P1_CHUNK;
  int v[P1_ITER], e[P1_ITER];
#pragma unroll
  for (int j = 0; j < P1_ITER; ++j) {
    int idx = base + j * 256 + t;
    if (idx < NNZ) {
      v[j] = v_idx[idx]; e[j] = e_idx[idx];
      atomicAdd(&he[e[j] / SPAN_E], 1);
      atomicAdd(&hv[v[j] / SPAN_V], 1);
    } else v[j] = -1;
  }
  __syncthreads();
  be[t] = he[t] ? atomicAdd(&ce[t], he[t]) : 0;
  bv[t] = hv[t] ? atomicAdd(&cv[t], hv[t]) : 0;
  __syncthreads();
#pragma unroll
  for (int j = 0; j < P1_ITER; ++j) {
    if (v[j] < 0) continue;
    int eb = e[j] / SPAN_E, vb = v[j] / SPAN_V;
    int se = be[eb] + atomicAdd(&le[eb], 1);
    int sv = bv[vb] + atomicAdd(&lv[vb], 1);
    if (se < (eb + 1) * CAP_E) Te[se] = ((unsigned)e[j] << 17) | (unsigned)v[j];
    if (sv < (vb + 1) * CAP_V) Tv[sv] = ((unsigned)v[j] << 15) | (unsigned)e[j];
  }
}

// ---------------- pass 2 merged: blocks [0,NB) vertex side (+prescale), [NB,2NB) edge side ----------------
__global__ __launch_bounds__(256) void k_sort(const int* __restrict__ ce, const int* __restrict__ cv,
                                              unsigned int* __restrict__ Te, unsigned int* __restrict__ Tv,
                                              int* __restrict__ cnt_e, float* __restrict__ invde,
                                              int* __restrict__ starts_e,
                                              int* __restrict__ cnt_v, float* __restrict__ risv,
                                              int* __restrict__ starts_v,
                                              const float* __restrict__ X, unsigned int* __restrict__ Xs) {
  __shared__ unsigned int raw[CAP_V];
  __shared__ int hist[SPAN_V], lcur[SPAN_V], loff[SPAN_V + 1];
  __shared__ float rv[SPAN_V];
  int t = threadIdx.x;
  if (blockIdx.x < NB) {
    int b = blockIdx.x;
    int v0 = b * SPAN_V;
    int span = N_NODES - v0; if (span > SPAN_V) span = SPAN_V;
    if (span <= 0) return;
    int n = cv[b] - b * CAP_V; if (n > CAP_V) n = CAP_V; if (n < 0) n = 0;
    for (int i = t; i < n; i += 256) raw[i] = Tv[b * CAP_V + i];
    for (int i = t; i < span; i += 256) { hist[i] = 0; lcur[i] = 0; }
    __syncthreads();
    for (int i = t; i < n; i += 256) atomicAdd(&hist[(int)(raw[i] >> 15) - v0], 1);
    __syncthreads();
    if (t == 0) { int run = 0; for (int i = 0; i < span; ++i) { loff[i] = run; run += hist[i]; } loff[span] = run; }
    __syncthreads();
    for (int i = t; i < n; i += 256) {
      unsigned int p = raw[i];
      int l = (int)(p >> 15) - v0;
      int slot = loff[l] + atomicAdd(&lcur[l], 1);
      Tv[b * CAP_V + slot] = p & 0x7FFFu;
    }
    for (int i = t; i < span; i += 256) {
      int d = hist[i];
      float r = d > 0 ? rsqrtf((float)d) : 0.0f;
      cnt_v[v0 + i] = d;
      risv[v0 + i] = r;
      rv[i] = r;
      starts_v[v0 + i] = b * CAP_V + loff[i];
    }
    __syncthreads();
    // fused prescale: Xs[v] = bf16(risv[v] * X[v])
    int total = span * DW;
    for (int idx = t; idx < total; idx += 256) {
      int vl = idx >> 6;
      float r = rv[vl];
      size_t gp = (size_t)(v0 + vl) * DW + (idx & 63);
      float2 x = *(const float2*)(X + gp * 2);
      Xs[gp] = pack_bf2(r * x.x, r * x.y);
    }
  } else {
    int b = blockIdx.x - NB;
    int e0 = b * SPAN_E;
    int span = N_EDGES - e0; if (span > SPAN_E) span = SPAN_E;
    if (span <= 0) return;
    int n = ce[b] - b * CAP_E; if (n > CAP_E) n = CAP_E; if (n < 0) n = 0;
    for (int i = t; i < n; i += 256) raw[i] = Te[b * CAP_E + i];
    for (int i = t; i < span; i += 256) { hist[i] = 0; lcur[i] = 0; }
    __syncthreads();
    for (int i = t; i < n; i += 256) atomicAdd(&hist[(int)(raw[i] >> 17) - e0], 1);
    __syncthreads();
    if (t == 0) { int run = 0; for (int i = 0; i < span; ++i) { loff[i] = run; run += hist[i]; } loff[span] = run; }
    __syncthreads();
    for (int i = t; i < n; i += 256) {
      unsigned int p = raw[i];
      int l = (int)(p >> 17) - e0;
      int slot = loff[l] + atomicAdd(&lcur[l], 1);
      Te[b * CAP_E + slot] = p & 0x1FFFFu;
    }
    for (int i = t; i < span; i += 256) {
      int d = hist[i];
      cnt_e[e0 + i] = d;
      invde[e0 + i] = d > 0 ? 1.0f / (float)d : 0.0f;
      starts_e[e0 + i] = b * CAP_E + loff[i];
    }
  }
}

// ---------------- phase A: Qeb[e] = bf16( sum Xs[v] );  qv[e] = sum risv[v] ----------------
__global__ void k_edge_gather(const unsigned int* __restrict__ Xs, const float* __restrict__ risv,
                              const int* __restrict__ starts_e, const int* __restrict__ cnt_e,
                              const unsigned int* __restrict__ members,
                              unsigned int* __restrict__ Qeb, float* __restrict__ qv) {
  int wid = (blockIdx.x * 256 + threadIdx.x) >> 6;   // one wave per edge
  int lane = threadIdx.x & 63;
  if (wid >= N_EDGES) return;
  int beg = __builtin_amdgcn_readfirstlane(starts_e[wid]);
  int end = beg + __builtin_amdgcn_readfirstlane(cnt_e[wid]);
  float ax = 0.f, ay = 0.f, q = 0.f;
  int i = beg;
  for (; i + 16 <= end; i += 16) {
    int vv[16]; unsigned int xx[16];
#pragma unroll
    for (int j = 0; j < 16; ++j) vv[j] = members[i + j];
#pragma unroll
    for (int j = 0; j < 16; ++j) xx[j] = Xs[(size_t)vv[j] * DW + lane];
#pragma unroll
    for (int j = 0; j < 16; ++j) q += risv[vv[j]];
#pragma unroll
    for (int j = 0; j < 16; ++j) {
      ax += __uint_as_float(xx[j] << 16);
      ay += __uint_as_float(xx[j] & 0xFFFF0000u);
    }
  }
  if (i + 8 <= end) {
    int vv[8]; unsigned int xx[8];
#pragma unroll
    for (int j = 0; j < 8; ++j) vv[j] = members[i + j];
#pragma unroll
    for (int j = 0; j < 8; ++j) xx[j] = Xs[(size_t)vv[j] * DW + lane];
#pragma unroll
    for (int j = 0; j < 8; ++j) q += risv[vv[j]];
#pragma unroll
    for (int j = 0; j < 8; ++j) {
      ax += __uint_as_float(xx[j] << 16);
      ay += __uint_as_float(xx[j] & 0xFFFF0000u);
    }
    i += 8;
  }
  for (; i < end; ++i) {
    int v = members[i];
    unsigned int x = Xs[(size_t)v * DW + lane];
    ax += __uint_as_float(x << 16);
    ay += __uint_as_float(x & 0xFFFF0000u);
    q += risv[v];
  }
  Qeb[(size_t)wid * DW + lane] = pack_bf2(ax, ay);
  if (lane == 0) qv[wid] = q;
}

// ---------------- MFMA GEMM: Yeb[e] = bf16( invde[e] * (Qeb[e] @ W + qv[e] * b) ) ----------------
// One wave per 16 edges. A-frag (16x16x32 bf16): lane l holds A[m=l&15][k=(l>>4)*8+j].
// B-frag: lane l holds B[k=(l>>4)*8+j][n=l&15] — served by Wtp[c][kp] packed pairs.
// D: col=lane&15, row=(lane>>4)*4+reg (verified layout).
__global__ __launch_bounds__(256) void k_gemm(const unsigned int* __restrict__ Qeb, const float* __restrict__ qv,
                                              const unsigned int* __restrict__ Wtp, const float* __restrict__ bias,
                                              const float* __restrict__ invde, unsigned short* __restrict__ Yeb) {
  int wid = (blockIdx.x * 256 + threadIdx.x) >> 6;
  int lane = threadIdx.x & 63;
  if (wid >= N_EDGES / 16) return;
  int e0 = wid * 16;
  int lrow = lane & 15, lhalf = lane >> 4;
  const unsigned int* arow = Qeb + (size_t)(e0 + lrow) * DW + lhalf * 4;
  f32x4 acc[8];
#pragma unroll
  for (int nt = 0; nt < 8; ++nt) acc[nt] = (f32x4){0.f, 0.f, 0.f, 0.f};
#pragma unroll
  for (int kt = 0; kt < 4; ++kt) {
    bf16x8 a = *(const bf16x8*)(arow + kt * 16);
#pragma unroll
    for (int nt = 0; nt < 8; ++nt) {
      bf16x8 b = *(const bf16x8*)(Wtp + (size_t)(nt * 16 + lrow) * DW + kt * 16 + lhalf * 4);
      acc[nt] = __builtin_amdgcn_mfma_f32_16x16x32_bf16(a, b, acc[nt], 0, 0, 0);
    }
  }
#pragma unroll
  for (int r = 0; r < 4; ++r) {
    int row = e0 + lhalf * 4 + r;
    float s = invde[row], q = qv[row];
#pragma unroll
    for (int nt = 0; nt < 8; ++nt) {
      int c = nt * 16 + lrow;
      float val = s * (acc[nt][r] + q * bias[c]);
      unsigned int u = __float_as_uint(val);
      u = (u + 0x7FFFu + ((u >> 16) & 1u)) >> 16;
      Yeb[(size_t)row * D + c] = (unsigned short)u;
    }
  }
}

// ---------------- phase B: out[v] = relu(risv[v] * sum Yeb[e]) ----------------
__global__ void k_vertex_gather(const unsigned int* __restrict__ Yeb, const float* __restrict__ risv,
                                const int* __restrict__ starts_v, const int* __restrict__ cnt_v,
                                const unsigned int* __restrict__ members,
                                float* __restrict__ out) {
  int wid = (blockIdx.x * 256 + threadIdx.x) >> 6;   // one wave per vertex
  int lane = threadIdx.x & 63;
  if (wid >= N_NODES) return;
  int beg = __builtin_amdgcn_readfirstlane(starts_v[wid]);
  int end = beg + __builtin_amdgcn_readfirstlane(cnt_v[wid]);
  float ax = 0.f, ay = 0.f;
  int i = beg;
  for (; i + 16 <= end; i += 16) {
    int ee[16]; unsigned int yy[16];
#pragma unroll
    for (int j = 0; j < 16; ++j) ee[j] = members[i + j];
#pragma unroll
    for (int j = 0; j < 16; ++j) yy[j] = Yeb[(size_t)ee[j] * DW + lane];
#pragma unroll
    for (int j = 0; j < 16; ++j) {
      ax += __uint_as_float(yy[j] << 16);
      ay += __uint_as_float(yy[j] & 0xFFFF0000u);
    }
  }
  if (i + 8 <= end) {
    int ee[8]; unsigned int yy[8];
#pragma unroll
    for (int j = 0; j < 8; ++j) ee[j] = members[i + j];
#pragma unroll
    for (int j = 0; j < 8; ++j) yy[j] = Yeb[(size_t)ee[j] * DW + lane];
#pragma unroll
    for (int j = 0; j < 8; ++j) {
      ax += __uint_as_float(yy[j] << 16);
      ay += __uint_as_float(yy[j] & 0xFFFF0000u);
    }
    i += 8;
  }
  for (; i < end; ++i) {
    unsigned int y = Yeb[(size_t)members[i] * DW + lane];
    ax += __uint_as_float(y << 16);
    ay += __uint_as_float(y & 0xFFFF0000u);
  }
  float s = risv[wid];
  float2 o; o.x = fmaxf(ax * s, 0.f); o.y = fmaxf(ay * s, 0.f);
  *(float2*)(out + (size_t)wid * D + lane * 2) = o;
}

extern "C" void kernel_launch(void* const* d_in, const int* in_sizes, int n_in,
                              void* d_out, int out_size, void* d_ws, size_t ws_size,
                              hipStream_t stream) {
  const float* X    = (const float*)d_in[0];
  const float* W    = (const float*)d_in[1];
  const float* bias = (const float*)d_in[2];
  const int* v_idx  = (const int*)d_in[3];
  const int* e_idx  = (const int*)d_in[4];
  float* out = (float*)d_out;

  char* p = (char*)d_ws;
  auto alloc = [&](size_t bytes) { char* r = p; p += (bytes + 255) & ~(size_t)255; return r; };
  unsigned int* Te  = (unsigned int*)alloc((size_t)NB * CAP_E * 4);
  unsigned int* Tv  = (unsigned int*)alloc((size_t)NB * CAP_V * 4);
  unsigned int* Xs  = (unsigned int*)alloc((size_t)N_NODES * DW * 4);
  unsigned int* Qeb = (unsigned int*)alloc((size_t)N_EDGES * DW * 4);
  unsigned int* Yeb = (unsigned int*)alloc((size_t)N_EDGES * DW * 4);
  unsigned int* Wtp = (unsigned int*)alloc((size_t)D * DW * 4);
  float* qv    = (float*)alloc((size_t)N_EDGES * 4);
  float* risv  = (float*)alloc((size_t)N_NODES * 4);
  float* invde = (float*)alloc((size_t)N_EDGES * 4);
  int* cnt_e    = (int*)alloc((size_t)N_EDGES * 4);
  int* cnt_v    = (int*)alloc((size_t)N_NODES * 4);
  int* starts_e = (int*)alloc((size_t)N_EDGES * 4);
  int* starts_v = (int*)alloc((size_t)N_NODES * 4);
  int* ce       = (int*)alloc(NB * 4);
  int* cv       = (int*)alloc(NB * 4);

  k_prep<<<(D * DW + 255) / 256, 256, 0, stream>>>(W, Wtp, ce, cv);
  k_bin<<<P1_BLOCKS, 256, 0, stream>>>(v_idx, e_idx, ce, cv, Te, Tv);
  k_sort<<<2 * NB, 256, 0, stream>>>(ce, cv, Te, Tv, cnt_e, invde, starts_e,
                                     cnt_v, risv, starts_v, X, Xs);
  k_edge_gather<<<N_EDGES / 4, 256, 0, stream>>>(Xs, risv, starts_e, cnt_e, Te, Qeb, qv);
  k_gemm<<<(N_EDGES / 16 + 3) / 4, 256, 0, stream>>>(Qeb, qv, Wtp, bias, invde, (unsigned short*)Yeb);
  k_vertex_gather<<<N_NODES / 4, 256, 0, stream>>>(Yeb, risv, starts_v, cnt_v, Tv, out);
}

// Round 7
// 278.640 us; speedup vs baseline: 1.1406x; 1.0389x over previous
//
#include <hip/hip_runtime.h>

#define N_NODES 100000
#define N_EDGES 20000
#define NNZ     1600000
#define D       128
#define DW      64                         // uints per bf16 row (2 ch per uint)

#define NB      256                        // buckets per side
#define CAP_E   8192
#define CAP_V   8192
#define SPAN_E  ((N_EDGES + NB - 1) / NB)  // 79
#define SPAN_V  ((N_NODES + NB - 1) / NB)  // 391
#define P1_CHUNK 8192
#define P1_ITER  (P1_CHUNK / 256)          // 32
#define P1_BLOCKS ((NNZ + P1_CHUNK - 1) / P1_CHUNK)  // 196

typedef __attribute__((ext_vector_type(8))) short bf16x8;
typedef __attribute__((ext_vector_type(4))) float f32x4;

__device__ __forceinline__ unsigned int pack_bf2(float lo, float hi) {
  unsigned int ul = __float_as_uint(lo), uh = __float_as_uint(hi);
  ul = (ul + 0x7FFFu + ((ul >> 16) & 1u)) >> 16;
  uh = (uh + 0x7FFFu + ((uh >> 16) & 1u)) & 0xFFFF0000u;
  return ul | uh;
}

// ---------------- prep: cursors + Wtp + dummy zero rows ----------------
__global__ __launch_bounds__(256) void k_prep(const float* __restrict__ W, unsigned int* __restrict__ Wtp,
                                              int* __restrict__ ce, int* __restrict__ cv,
                                              unsigned int* __restrict__ Xs, unsigned int* __restrict__ Yeb,
                                              float* __restrict__ risv) {
  int t = threadIdx.x;
  if (blockIdx.x == 0) {
    ce[t] = t * CAP_E; cv[t] = t * CAP_V;
    if (t < DW) { Xs[(size_t)N_NODES * DW + t] = 0u; Yeb[(size_t)N_EDGES * DW + t] = 0u; }
    if (t == 0) risv[N_NODES] = 0.f;
  }
  int idx = blockIdx.x * 256 + t;
  if (idx < D * DW) {
    int c = idx & 127, kp = idx >> 7;                 // coalesced W row reads
    float lo = W[(size_t)(2 * kp) * D + c];
    float hi = W[(size_t)(2 * kp + 1) * D + c];
    Wtp[c * DW + kp] = pack_bf2(lo, hi);
  }
}

// ---------------- pass 1: bin incidences ----------------
__global__ __launch_bounds__(256) void k_bin(const int* __restrict__ v_idx, const int* __restrict__ e_idx,
                                             int* __restrict__ ce, int* __restrict__ cv,
                                             unsigned int* __restrict__ Te, unsigned int* __restrict__ Tv) {
  __shared__ int he[NB], hv[NB], be[NB], bv[NB], le[NB], lv[NB];
  int t = threadIdx.x;
  he[t] = 0; hv[t] = 0; le[t] = 0; lv[t] = 0;
  __syncthreads();
  int base = blockIdx.x * P1_CHUNK;
  int v[P1_ITER], e[P1_ITER];
#pragma unroll
  for (int j = 0; j < P1_ITER; ++j) {
    int idx = base + j * 256 + t;
    if (idx < NNZ) {
      v[j] = v_idx[idx]; e[j] = e_idx[idx];
      atomicAdd(&he[e[j] / SPAN_E], 1);
      atomicAdd(&hv[v[j] / SPAN_V], 1);
    } else v[j] = -1;
  }
  __syncthreads();
  be[t] = he[t] ? atomicAdd(&ce[t], he[t]) : 0;
  bv[t] = hv[t] ? atomicAdd(&cv[t], hv[t]) : 0;
  __syncthreads();
#pragma unroll
  for (int j = 0; j < P1_ITER; ++j) {
    if (v[j] < 0) continue;
    int eb = e[j] / SPAN_E, vb = v[j] / SPAN_V;
    int se = be[eb] + atomicAdd(&le[eb], 1);
    int sv = bv[vb] + atomicAdd(&lv[vb], 1);
    if (se < (eb + 1) * CAP_E) Te[se] = ((unsigned)e[j] << 17) | (unsigned)v[j];
    if (sv < (vb + 1) * CAP_V) Tv[sv] = ((unsigned)v[j] << 15) | (unsigned)e[j];
  }
}

// ---------------- pass 2 merged: blocks [0,NB) vertex side (+prescale), [NB,2NB) edge side ----------------
__global__ __launch_bounds__(256) void k_sort(const int* __restrict__ ce, const int* __restrict__ cv,
                                              unsigned int* __restrict__ Te, unsigned int* __restrict__ Tv,
                                              int* __restrict__ cnt_e, float* __restrict__ invde,
                                              int* __restrict__ starts_e,
                                              int* __restrict__ cnt_v, float* __restrict__ risv,
                                              int* __restrict__ starts_v,
                                              const float* __restrict__ X, unsigned int* __restrict__ Xs) {
  __shared__ unsigned int raw[CAP_V];
  __shared__ int hist[SPAN_V], lcur[SPAN_V], loff[SPAN_V + 1];
  __shared__ float rv[SPAN_V];
  int t = threadIdx.x;
  if (blockIdx.x < NB) {
    int b = blockIdx.x;
    int v0 = b * SPAN_V;
    int span = N_NODES - v0; if (span > SPAN_V) span = SPAN_V;
    if (span <= 0) return;
    int n = cv[b] - b * CAP_V; if (n > CAP_V) n = CAP_V; if (n < 0) n = 0;
    for (int i = t; i < n; i += 256) raw[i] = Tv[b * CAP_V + i];
    for (int i = t; i < span; i += 256) { hist[i] = 0; lcur[i] = 0; }
    __syncthreads();
    for (int i = t; i < n; i += 256) atomicAdd(&hist[(int)(raw[i] >> 15) - v0], 1);
    __syncthreads();
    if (t == 0) { int run = 0; for (int i = 0; i < span; ++i) { loff[i] = run; run += hist[i]; } loff[span] = run; }
    __syncthreads();
    for (int i = t; i < n; i += 256) {
      unsigned int p = raw[i];
      int l = (int)(p >> 15) - v0;
      int slot = loff[l] + atomicAdd(&lcur[l], 1);
      Tv[b * CAP_V + slot] = p & 0x7FFFu;
    }
    for (int i = t; i < span; i += 256) {
      int d = hist[i];
      float r = d > 0 ? rsqrtf((float)d) : 0.0f;
      cnt_v[v0 + i] = d;
      risv[v0 + i] = r;
      rv[i] = r;
      starts_v[v0 + i] = b * CAP_V + loff[i];
    }
    __syncthreads();
    // fused prescale: Xs[v] = bf16(risv[v] * X[v])
    int total = span * DW;
    for (int idx = t; idx < total; idx += 256) {
      int vl = idx >> 6;
      float r = rv[vl];
      size_t gp = (size_t)(v0 + vl) * DW + (idx & 63);
      float2 x = *(const float2*)(X + gp * 2);
      Xs[gp] = pack_bf2(r * x.x, r * x.y);
    }
  } else {
    int b = blockIdx.x - NB;
    int e0 = b * SPAN_E;
    int span = N_EDGES - e0; if (span > SPAN_E) span = SPAN_E;
    if (span <= 0) return;
    int n = ce[b] - b * CAP_E; if (n > CAP_E) n = CAP_E; if (n < 0) n = 0;
    for (int i = t; i < n; i += 256) raw[i] = Te[b * CAP_E + i];
    for (int i = t; i < span; i += 256) { hist[i] = 0; lcur[i] = 0; }
    __syncthreads();
    for (int i = t; i < n; i += 256) atomicAdd(&hist[(int)(raw[i] >> 17) - e0], 1);
    __syncthreads();
    if (t == 0) { int run = 0; for (int i = 0; i < span; ++i) { loff[i] = run; run += hist[i]; } loff[span] = run; }
    __syncthreads();
    for (int i = t; i < n; i += 256) {
      unsigned int p = raw[i];
      int l = (int)(p >> 17) - e0;
      int slot = loff[l] + atomicAdd(&lcur[l], 1);
      Te[b * CAP_E + slot] = p & 0x1FFFFu;
    }
    for (int i = t; i < span; i += 256) {
      int d = hist[i];
      cnt_e[e0 + i] = d;
      invde[e0 + i] = d > 0 ? 1.0f / (float)d : 0.0f;
      starts_e[e0 + i] = b * CAP_E + loff[i];
    }
  }
}

// ---------------- phase A: 4 edges per wave, 16 lanes x uint4 per row ----------------
__global__ __launch_bounds__(256) void k_edge_gather(const unsigned int* __restrict__ Xs, const float* __restrict__ risv,
                              const int* __restrict__ starts_e, const int* __restrict__ cnt_e,
                              const unsigned int* __restrict__ members,
                              unsigned int* __restrict__ Qeb, float* __restrict__ qv) {
  int wv = (blockIdx.x * 256 + threadIdx.x) >> 6;
  int lane = threadIdx.x & 63;
  int g = lane >> 4, l16 = lane & 15;
  int e = wv * 4 + g;
  if (e >= N_EDGES) return;                         // N_EDGES%4==0: wave-uniform
  int beg = starts_e[e];
  int cnt = cnt_e[e];
  int maxc = cnt;
  maxc = max(maxc, __shfl_xor(maxc, 16));
  maxc = max(maxc, __shfl_xor(maxc, 32));
  float a0=0,a1=0,a2=0,a3=0,a4=0,a5=0,a6=0,a7=0,q=0.f;
  for (int i = 0; i < maxc; i += 8) {
    int vv[8];
#pragma unroll
    for (int j = 0; j < 8; ++j) {
      int idx = i + j;
      int m = (int)members[beg + idx];              // slack read past cnt stays in ws
      vv[j] = (idx < cnt) ? m : N_NODES;            // dummy zero row
    }
    uint4 xx[8];
#pragma unroll
    for (int j = 0; j < 8; ++j) xx[j] = *(const uint4*)(Xs + (size_t)vv[j] * DW + l16 * 4);
#pragma unroll
    for (int j = 0; j < 8; ++j) q += risv[vv[j]];   // risv[N_NODES]=0
#pragma unroll
    for (int j = 0; j < 8; ++j) {
      a0 += __uint_as_float(xx[j].x << 16); a1 += __uint_as_float(xx[j].x & 0xFFFF0000u);
      a2 += __uint_as_float(xx[j].y << 16); a3 += __uint_as_float(xx[j].y & 0xFFFF0000u);
      a4 += __uint_as_float(xx[j].z << 16); a5 += __uint_as_float(xx[j].z & 0xFFFF0000u);
      a6 += __uint_as_float(xx[j].w << 16); a7 += __uint_as_float(xx[j].w & 0xFFFF0000u);
    }
  }
  uint4 o;
  o.x = pack_bf2(a0, a1); o.y = pack_bf2(a2, a3);
  o.z = pack_bf2(a4, a5); o.w = pack_bf2(a6, a7);
  *(uint4*)(Qeb + (size_t)e * DW + l16 * 4) = o;
  if (l16 == 0) qv[e] = q;
}

// ---------------- MFMA GEMM: Yeb[e] = bf16( invde[e] * (Qeb[e] @ W + qv[e] * b) ) ----------------
__global__ __launch_bounds__(256) void k_gemm(const unsigned int* __restrict__ Qeb, const float* __restrict__ qv,
                                              const unsigned int* __restrict__ Wtp, const float* __restrict__ bias,
                                              const float* __restrict__ invde, unsigned short* __restrict__ Yeb) {
  int wid = (blockIdx.x * 256 + threadIdx.x) >> 6;
  int lane = threadIdx.x & 63;
  if (wid >= N_EDGES / 16) return;
  int e0 = wid * 16;
  int lrow = lane & 15, lhalf = lane >> 4;
  const unsigned int* arow = Qeb + (size_t)(e0 + lrow) * DW + lhalf * 4;
  f32x4 acc[8];
#pragma unroll
  for (int nt = 0; nt < 8; ++nt) acc[nt] = (f32x4){0.f, 0.f, 0.f, 0.f};
#pragma unroll
  for (int kt = 0; kt < 4; ++kt) {
    bf16x8 a = *(const bf16x8*)(arow + kt * 16);
#pragma unroll
    for (int nt = 0; nt < 8; ++nt) {
      bf16x8 b = *(const bf16x8*)(Wtp + (size_t)(nt * 16 + lrow) * DW + kt * 16 + lhalf * 4);
      acc[nt] = __builtin_amdgcn_mfma_f32_16x16x32_bf16(a, b, acc[nt], 0, 0, 0);
    }
  }
#pragma unroll
  for (int r = 0; r < 4; ++r) {
    int row = e0 + lhalf * 4 + r;
    float s = invde[row], q = qv[row];
#pragma unroll
    for (int nt = 0; nt < 8; ++nt) {
      int c = nt * 16 + lrow;
      float val = s * (acc[nt][r] + q * bias[c]);
      unsigned int u = __float_as_uint(val);
      u = (u + 0x7FFFu + ((u >> 16) & 1u)) >> 16;
      Yeb[(size_t)row * D + c] = (unsigned short)u;
    }
  }
}

// ---------------- phase B: 4 vertices per wave, 16 lanes x uint4 per row ----------------
__global__ __launch_bounds__(256) void k_vertex_gather(const unsigned int* __restrict__ Yeb, const float* __restrict__ risv,
                                const int* __restrict__ starts_v, const int* __restrict__ cnt_v,
                                const unsigned int* __restrict__ members,
                                float* __restrict__ out) {
  int wv = (blockIdx.x * 256 + threadIdx.x) >> 6;
  int lane = threadIdx.x & 63;
  int g = lane >> 4, l16 = lane & 15;
  int v = wv * 4 + g;
  if (v >= N_NODES) return;                         // N_NODES%4==0: wave-uniform
  int beg = starts_v[v];
  int cnt = cnt_v[v];
  int maxc = cnt;
  maxc = max(maxc, __shfl_xor(maxc, 16));
  maxc = max(maxc, __shfl_xor(maxc, 32));
  float a0=0,a1=0,a2=0,a3=0,a4=0,a5=0,a6=0,a7=0;
  for (int i = 0; i < maxc; i += 8) {
    int ee[8];
#pragma unroll
    for (int j = 0; j < 8; ++j) {
      int idx = i + j;
      int m = (int)members[beg + idx];
      ee[j] = (idx < cnt) ? m : N_EDGES;            // dummy zero row
    }
    uint4 yy[8];
#pragma unroll
    for (int j = 0; j < 8; ++j) yy[j] = *(const uint4*)(Yeb + (size_t)ee[j] * DW + l16 * 4);
#pragma unroll
    for (int j = 0; j < 8; ++j) {
      a0 += __uint_as_float(yy[j].x << 16); a1 += __uint_as_float(yy[j].x & 0xFFFF0000u);
      a2 += __uint_as_float(yy[j].y << 16); a3 += __uint_as_float(yy[j].y & 0xFFFF0000u);
      a4 += __uint_as_float(yy[j].z << 16); a5 += __uint_as_float(yy[j].z & 0xFFFF0000u);
      a6 += __uint_as_float(yy[j].w << 16); a7 += __uint_as_float(yy[j].w & 0xFFFF0000u);
    }
  }
  float s = risv[v];
  float4 o0, o1;
  o0.x = fmaxf(a0 * s, 0.f); o0.y = fmaxf(a1 * s, 0.f);
  o0.z = fmaxf(a2 * s, 0.f); o0.w = fmaxf(a3 * s, 0.f);
  o1.x = fmaxf(a4 * s, 0.f); o1.y = fmaxf(a5 * s, 0.f);
  o1.z = fmaxf(a6 * s, 0.f); o1.w = fmaxf(a7 * s, 0.f);
  float* orow = out + (size_t)v * D + l16 * 8;
  *(float4*)orow = o0;
  *(float4*)(orow + 4) = o1;
}

extern "C" void kernel_launch(void* const* d_in, const int* in_sizes, int n_in,
                              void* d_out, int out_size, void* d_ws, size_t ws_size,
                              hipStream_t stream) {
  const float* X    = (const float*)d_in[0];
  const float* W    = (const float*)d_in[1];
  const float* bias = (const float*)d_in[2];
  const int* v_idx  = (const int*)d_in[3];
  const int* e_idx  = (const int*)d_in[4];
  float* out = (float*)d_out;

  char* p = (char*)d_ws;
  auto alloc = [&](size_t bytes) { char* r = p; p += (bytes + 255) & ~(size_t)255; return r; };
  unsigned int* Te  = (unsigned int*)alloc((size_t)NB * CAP_E * 4);
  unsigned int* Tv  = (unsigned int*)alloc((size_t)NB * CAP_V * 4);
  unsigned int* Xs  = (unsigned int*)alloc((size_t)(N_NODES + 1) * DW * 4);
  unsigned int* Qeb = (unsigned int*)alloc((size_t)N_EDGES * DW * 4);
  unsigned int* Yeb = (unsigned int*)alloc((size_t)(N_EDGES + 1) * DW * 4);
  unsigned int* Wtp = (unsigned int*)alloc((size_t)D * DW * 4);
  float* qv    = (float*)alloc((size_t)N_EDGES * 4);
  float* risv  = (float*)alloc((size_t)(N_NODES + 1) * 4);
  float* invde = (float*)alloc((size_t)N_EDGES * 4);
  int* cnt_e    = (int*)alloc((size_t)N_EDGES * 4);
  int* cnt_v    = (int*)alloc((size_t)N_NODES * 4);
  int* starts_e = (int*)alloc((size_t)N_EDGES * 4);
  int* starts_v = (int*)alloc((size_t)N_NODES * 4);
  int* ce       = (int*)alloc(NB * 4);
  int* cv       = (int*)alloc(NB * 4);

  k_prep<<<(D * DW + 255) / 256, 256, 0, stream>>>(W, Wtp, ce, cv, Xs, Yeb, risv);
  k_bin<<<P1_BLOCKS, 256, 0, stream>>>(v_idx, e_idx, ce, cv, Te, Tv);
  k_sort<<<2 * NB, 256, 0, stream>>>(ce, cv, Te, Tv, cnt_e, invde, starts_e,
                                     cnt_v, risv, starts_v, X, Xs);
  k_edge_gather<<<(N_EDGES / 4 + 3) / 4, 256, 0, stream>>>(Xs, risv, starts_e, cnt_e, Te, Qeb, qv);
  k_gemm<<<(N_EDGES / 16 + 3) / 4, 256, 0, stream>>>(Qeb, qv, Wtp, bias, invde, (unsigned short*)Yeb);
  k_vertex_gather<<<(N_NODES / 4 + 3) / 4, 256, 0, stream>>>(Yeb, risv, starts_v, cnt_v, Tv, out);
}

// Round 9
// 268.223 us; speedup vs baseline: 1.1849x; 1.0388x over previous
//
#include <hip/hip_runtime.h>

#define N_NODES 100000
#define N_EDGES 20000
#define NNZ     1600000
#define D       128
#define DW      64                         // uints per bf16 row (2 ch per uint)

#define NB      256                        // buckets per side
#define CAP_E   8192
#define CAP_V   8192
#define SPAN_E  ((N_EDGES + NB - 1) / NB)  // 79
#define SPAN_V  ((N_NODES + NB - 1) / NB)  // 391
#define P1_CHUNK 8192
#define P1_ITER  (P1_CHUNK / 256)          // 32
#define P1_BLOCKS ((NNZ + P1_CHUNK - 1) / P1_CHUNK)  // 196

typedef __attribute__((ext_vector_type(8))) short bf16x8;
typedef __attribute__((ext_vector_type(4))) float f32x4;

__device__ __forceinline__ unsigned int pack_bf2(float lo, float hi) {
  unsigned int ul = __float_as_uint(lo), uh = __float_as_uint(hi);
  ul = (ul + 0x7FFFu + ((ul >> 16) & 1u)) >> 16;
  uh = (uh + 0x7FFFu + ((uh >> 16) & 1u)) & 0xFFFF0000u;
  return ul | uh;
}

// ---------------- zero bucket cursors (graph-capture-safe, replaces hipMemsetAsync) ----------------
__global__ void k_zero_cursors(int* __restrict__ cur) {
  cur[threadIdx.x] = 0;                  // 512 = 2*NB
}

// ---------------- pass 1: bin incidences (cursors RELATIVE) ----------------
__global__ __launch_bounds__(256) void k_bin(const int* __restrict__ v_idx, const int* __restrict__ e_idx,
                                             int* __restrict__ ce, int* __restrict__ cv,
                                             unsigned int* __restrict__ Te, unsigned int* __restrict__ Tv) {
  __shared__ int he[NB], hv[NB], be[NB], bv[NB], le[NB], lv[NB];
  int t = threadIdx.x;
  he[t] = 0; hv[t] = 0; le[t] = 0; lv[t] = 0;
  __syncthreads();
  int base = blockIdx.x * P1_CHUNK;
  int v[P1_ITER], e[P1_ITER];
#pragma unroll
  for (int j = 0; j < P1_ITER; ++j) {
    int idx = base + j * 256 + t;
    if (idx < NNZ) {
      v[j] = v_idx[idx]; e[j] = e_idx[idx];
      atomicAdd(&he[e[j] / SPAN_E], 1);
      atomicAdd(&hv[v[j] / SPAN_V], 1);
    } else v[j] = -1;
  }
  __syncthreads();
  be[t] = he[t] ? atomicAdd(&ce[t], he[t]) : 0;
  bv[t] = hv[t] ? atomicAdd(&cv[t], hv[t]) : 0;
  __syncthreads();
#pragma unroll
  for (int j = 0; j < P1_ITER; ++j) {
    if (v[j] < 0) continue;
    int eb = e[j] / SPAN_E, vb = v[j] / SPAN_V;
    int se = be[eb] + atomicAdd(&le[eb], 1);
    int sv = bv[vb] + atomicAdd(&lv[vb], 1);
    if (se < CAP_E) Te[(size_t)eb * CAP_E + se] = ((unsigned)e[j] << 17) | (unsigned)v[j];
    if (sv < CAP_V) Tv[(size_t)vb * CAP_V + sv] = ((unsigned)v[j] << 15) | (unsigned)e[j];
  }
}

// ---------------- pass 2 merged: [0,NB) vertex (+prescale), [NB,2NB) edge, [2NB,2NB+32) Wtp/dummies ----------------
__global__ __launch_bounds__(256) void k_sort(const int* __restrict__ ce, const int* __restrict__ cv,
                                              unsigned int* __restrict__ Te, unsigned int* __restrict__ Tv,
                                              int* __restrict__ cnt_e, float* __restrict__ invde,
                                              int* __restrict__ starts_e,
                                              int* __restrict__ cnt_v, float* __restrict__ risv,
                                              int* __restrict__ starts_v,
                                              const float* __restrict__ X, unsigned int* __restrict__ Xs,
                                              const float* __restrict__ W, unsigned int* __restrict__ Wtp,
                                              unsigned int* __restrict__ Yeb) {
  __shared__ unsigned int raw[CAP_V];
  __shared__ int hist[SPAN_V], lcur[SPAN_V], loff[SPAN_V + 1];
  __shared__ int sd[256];
  __shared__ float rv[SPAN_V];
  int t = threadIdx.x;
  if (blockIdx.x >= 2 * NB) {
    int bp = blockIdx.x - 2 * NB;
    if (bp == 0) {
      if (t < DW) { Xs[(size_t)N_NODES * DW + t] = 0u; Yeb[(size_t)N_EDGES * DW + t] = 0u; }
      if (t == 0) risv[N_NODES] = 0.f;
    }
    int idx = bp * 256 + t;
    if (idx < D * DW) {
      int c = idx & 127, kp = idx >> 7;
      float lo = W[(size_t)(2 * kp) * D + c];
      float hi = W[(size_t)(2 * kp + 1) * D + c];
      Wtp[c * DW + kp] = pack_bf2(lo, hi);
    }
    return;
  }
  if (blockIdx.x < NB) {
    int b = blockIdx.x;
    int v0 = b * SPAN_V;
    int span = N_NODES - v0; if (span > SPAN_V) span = SPAN_V;
    if (span <= 0) return;
    int n = cv[b]; if (n > CAP_V) n = CAP_V; if (n < 0) n = 0;
    for (int i = t; i < n; i += 256) raw[i] = Tv[(size_t)b * CAP_V + i];
    for (int i = t; i < span; i += 256) { hist[i] = 0; lcur[i] = 0; }
    __syncthreads();
    for (int i = t; i < n; i += 256) atomicAdd(&hist[(int)(raw[i] >> 15) - v0], 1);
    __syncthreads();
    {  // parallel exclusive scan of hist[0..span) into loff
      int i0 = 2 * t, i1 = 2 * t + 1;
      int s0 = (i0 < span) ? hist[i0] : 0;
      int s1 = (i1 < span) ? hist[i1] : 0;
      int mysum = s0 + s1;
      sd[t] = mysum; __syncthreads();
      for (int off = 1; off < 256; off <<= 1) {
        int add = (t >= off) ? sd[t - off] : 0;
        __syncthreads(); sd[t] += add; __syncthreads();
      }
      int bse = sd[t] - mysum;
      if (i0 < span) loff[i0] = bse;
      if (i1 < span) loff[i1] = bse + s0;
      __syncthreads();
    }
    for (int i = t; i < n; i += 256) {
      unsigned int p = raw[i];
      int l = (int)(p >> 15) - v0;
      int slot = loff[l] + atomicAdd(&lcur[l], 1);
      Tv[(size_t)b * CAP_V + slot] = p & 0x7FFFu;
    }
    for (int i = t; i < span; i += 256) {
      int d = hist[i];
      float r = d > 0 ? rsqrtf((float)d) : 0.0f;
      cnt_v[v0 + i] = d;
      risv[v0 + i] = r;
      rv[i] = r;
      starts_v[v0 + i] = b * CAP_V + loff[i];
    }
    __syncthreads();
    // fused prescale: Xs[v] = bf16(risv[v] * X[v])
    int total = span * DW;
    for (int idx = t; idx < total; idx += 256) {
      int vl = idx >> 6;
      float r = rv[vl];
      size_t gp = (size_t)(v0 + vl) * DW + (idx & 63);
      float2 x = *(const float2*)(X + gp * 2);
      Xs[gp] = pack_bf2(r * x.x, r * x.y);
    }
  } else {
    int b = blockIdx.x - NB;
    int e0 = b * SPAN_E;
    int span = N_EDGES - e0; if (span > SPAN_E) span = SPAN_E;
    if (span <= 0) return;
    int n = ce[b]; if (n > CAP_E) n = CAP_E; if (n < 0) n = 0;
    for (int i = t; i < n; i += 256) raw[i] = Te[(size_t)b * CAP_E + i];
    for (int i = t; i < span; i += 256) { hist[i] = 0; lcur[i] = 0; }
    __syncthreads();
    for (int i = t; i < n; i += 256) atomicAdd(&hist[(int)(raw[i] >> 17) - e0], 1);
    __syncthreads();
    {  // parallel exclusive scan
      int i0 = 2 * t, i1 = 2 * t + 1;
      int s0 = (i0 < span) ? hist[i0] : 0;
      int s1 = (i1 < span) ? hist[i1] : 0;
      int mysum = s0 + s1;
      sd[t] = mysum; __syncthreads();
      for (int off = 1; off < 256; off <<= 1) {
        int add = (t >= off) ? sd[t - off] : 0;
        __syncthreads(); sd[t] += add; __syncthreads();
      }
      int bse = sd[t] - mysum;
      if (i0 < span) loff[i0] = bse;
      if (i1 < span) loff[i1] = bse + s0;
      __syncthreads();
    }
    for (int i = t; i < n; i += 256) {
      unsigned int p = raw[i];
      int l = (int)(p >> 17) - e0;
      int slot = loff[l] + atomicAdd(&lcur[l], 1);
      Te[(size_t)b * CAP_E + slot] = p & 0x1FFFFu;
    }
    for (int i = t; i < span; i += 256) {
      int d = hist[i];
      cnt_e[e0 + i] = d;
      invde[e0 + i] = d > 0 ? 1.0f / (float)d : 0.0f;
      starts_e[e0 + i] = b * CAP_E + loff[i];
    }
  }
}

// ---------------- fused phase A + GEMM: 16 edges per block (4 waves x 4 edges), LDS-staged MFMA ----------------
__global__ __launch_bounds__(256) void k_eg_gemm(const unsigned int* __restrict__ Xs, const float* __restrict__ risv,
                                                 const int* __restrict__ starts_e, const int* __restrict__ cnt_e,
                                                 const unsigned int* __restrict__ members,
                                                 const unsigned int* __restrict__ Wtp, const float* __restrict__ bias,
                                                 const float* __restrict__ invde, unsigned short* __restrict__ Yeb) {
  __shared__ unsigned int Qls[16][DW];   // XOR-swizzled: row r, slot s stored at (s^r)
  __shared__ float qls[16], ivls[16];
  int tid = threadIdx.x;
  int wv = tid >> 6, lane = tid & 63;
  int g = lane >> 4, l16 = lane & 15;
  int row = wv * 4 + g;                  // 0..15
  int e = blockIdx.x * 16 + row;         // grid exact: 1250*16 = 20000
  int beg = starts_e[e];
  int cnt = cnt_e[e];
  int maxc = cnt;
  maxc = max(maxc, __shfl_xor(maxc, 16));
  maxc = max(maxc, __shfl_xor(maxc, 32));
  float a0=0,a1=0,a2=0,a3=0,a4=0,a5=0,a6=0,a7=0,q=0.f;
  for (int i = 0; i < maxc; i += 8) {
    int vv[8];
#pragma unroll
    for (int j = 0; j < 8; ++j) {
      int idx = i + j;
      int m = (int)members[beg + idx];   // slack reads stay inside padded ws
      vv[j] = (idx < cnt) ? m : N_NODES; // dummy zero row
    }
    uint4 xx[8];
#pragma unroll
    for (int j = 0; j < 8; ++j) xx[j] = *(const uint4*)(Xs + (size_t)vv[j] * DW + l16 * 4);
#pragma unroll
    for (int j = 0; j < 8; ++j) q += risv[vv[j]];   // risv[N_NODES]=0
#pragma unroll
    for (int j = 0; j < 8; ++j) {
      a0 += __uint_as_float(xx[j].x << 16); a1 += __uint_as_float(xx[j].x & 0xFFFF0000u);
      a2 += __uint_as_float(xx[j].y << 16); a3 += __uint_as_float(xx[j].y & 0xFFFF0000u);
      a4 += __uint_as_float(xx[j].z << 16); a5 += __uint_as_float(xx[j].z & 0xFFFF0000u);
      a6 += __uint_as_float(xx[j].w << 16); a7 += __uint_as_float(xx[j].w & 0xFFFF0000u);
    }
  }
  uint4 o;
  o.x = pack_bf2(a0, a1); o.y = pack_bf2(a2, a3);
  o.z = pack_bf2(a4, a5); o.w = pack_bf2(a6, a7);
  *(uint4*)&Qls[row][(l16 ^ row) * 4] = o;
  if (l16 == 0) { qls[row] = q; ivls[row] = invde[e]; }
  __syncthreads();
  // GEMM: wave wv computes n-tiles {2wv, 2wv+1}; A from LDS (swizzle-read), B from L2-hot Wtp
  f32x4 acc[2];
  acc[0] = (f32x4){0.f,0.f,0.f,0.f}; acc[1] = (f32x4){0.f,0.f,0.f,0.f};
#pragma unroll
  for (int kt = 0; kt < 4; ++kt) {
    int s = kt * 4 + g;                  // slot 0..15 (g == lhalf)
    bf16x8 a = *(const bf16x8*)&Qls[l16][(s ^ l16) * 4];
#pragma unroll
    for (int n = 0; n < 2; ++n) {
      int nt = wv * 2 + n;
      bf16x8 b = *(const bf16x8*)(Wtp + (size_t)(nt * 16 + l16) * DW + kt * 16 + g * 4);
      acc[n] = __builtin_amdgcn_mfma_f32_16x16x32_bf16(a, b, acc[n], 0, 0, 0);
    }
  }
#pragma unroll
  for (int r = 0; r < 4; ++r) {
    int lrow = g * 4 + r;                // C-layout row within 16
    int erow = blockIdx.x * 16 + lrow;
    float s = ivls[lrow], qq = qls[lrow];
#pragma unroll
    for (int n = 0; n < 2; ++n) {
      int c = (wv * 2 + n) * 16 + l16;
      float val = s * (acc[n][r] + qq * bias[c]);
      unsigned int u = __float_as_uint(val);
      u = (u + 0x7FFFu + ((u >> 16) & 1u)) >> 16;
      Yeb[(size_t)erow * D + c] = (unsigned short)u;
    }
  }
}

// ---------------- phase B: 4 vertices per wave, 16 lanes x uint4 per row ----------------
__global__ __launch_bounds__(256) void k_vertex_gather(const unsigned int* __restrict__ Yeb, const float* __restrict__ risv,
                                const int* __restrict__ starts_v, const int* __restrict__ cnt_v,
                                const unsigned int* __restrict__ members,
                                float* __restrict__ out) {
  int wv = (blockIdx.x * 256 + threadIdx.x) >> 6;
  int lane = threadIdx.x & 63;
  int g = lane >> 4, l16 = lane & 15;
  int v = wv * 4 + g;
  if (v >= N_NODES) return;
  int beg = starts_v[v];
  int cnt = cnt_v[v];
  int maxc = cnt;
  maxc = max(maxc, __shfl_xor(maxc, 16));
  maxc = max(maxc, __shfl_xor(maxc, 32));
  float a0=0,a1=0,a2=0,a3=0,a4=0,a5=0,a6=0,a7=0;
  for (int i = 0; i < maxc; i += 8) {
    int ee[8];
#pragma unroll
    for (int j = 0; j < 8; ++j) {
      int idx = i + j;
      int m = (int)members[beg + idx];
      ee[j] = (idx < cnt) ? m : N_EDGES;            // dummy zero row
    }
    uint4 yy[8];
#pragma unroll
    for (int j = 0; j < 8; ++j) yy[j] = *(const uint4*)(Yeb + (size_t)ee[j] * DW + l16 * 4);
#pragma unroll
    for (int j = 0; j < 8; ++j) {
      a0 += __uint_as_float(yy[j].x << 16); a1 += __uint_as_float(yy[j].x & 0xFFFF0000u);
      a2 += __uint_as_float(yy[j].y << 16); a3 += __uint_as_float(yy[j].y & 0xFFFF0000u);
      a4 += __uint_as_float(yy[j].z << 16); a5 += __uint_as_float(yy[j].z & 0xFFFF0000u);
      a6 += __uint_as_float(yy[j].w << 16); a7 += __uint_as_float(yy[j].w & 0xFFFF0000u);
    }
  }
  float s = risv[v];
  float4 o0, o1;
  o0.x = fmaxf(a0 * s, 0.f); o0.y = fmaxf(a1 * s, 0.f);
  o0.z = fmaxf(a2 * s, 0.f); o0.w = fmaxf(a3 * s, 0.f);
  o1.x = fmaxf(a4 * s, 0.f); o1.y = fmaxf(a5 * s, 0.f);
  o1.z = fmaxf(a6 * s, 0.f); o1.w = fmaxf(a7 * s, 0.f);
  float* orow = out + (size_t)v * D + l16 * 8;
  *(float4*)orow = o0;
  *(float4*)(orow + 4) = o1;
}

extern "C" void kernel_launch(void* const* d_in, const int* in_sizes, int n_in,
                              void* d_out, int out_size, void* d_ws, size_t ws_size,
                              hipStream_t stream) {
  const float* X    = (const float*)d_in[0];
  const float* W    = (const float*)d_in[1];
  const float* bias = (const float*)d_in[2];
  const int* v_idx  = (const int*)d_in[3];
  const int* e_idx  = (const int*)d_in[4];
  float* out = (float*)d_out;

  char* p = (char*)d_ws;
  auto alloc = [&](size_t bytes) { char* r = p; p += (bytes + 255) & ~(size_t)255; return r; };
  unsigned int* Te  = (unsigned int*)alloc(((size_t)NB + 1) * CAP_E * 4);   // +1 bucket slack pad
  unsigned int* Tv  = (unsigned int*)alloc(((size_t)NB + 1) * CAP_V * 4);
  unsigned int* Xs  = (unsigned int*)alloc((size_t)(N_NODES + 1) * DW * 4);
  unsigned int* Yeb = (unsigned int*)alloc((size_t)(N_EDGES + 1) * DW * 4);
  unsigned int* Wtp = (unsigned int*)alloc((size_t)D * DW * 4);
  float* risv  = (float*)alloc((size_t)(N_NODES + 1) * 4);
  float* invde = (float*)alloc((size_t)N_EDGES * 4);
  int* cnt_e    = (int*)alloc((size_t)N_EDGES * 4);
  int* cnt_v    = (int*)alloc((size_t)N_NODES * 4);
  int* starts_e = (int*)alloc((size_t)N_EDGES * 4);
  int* starts_v = (int*)alloc((size_t)N_NODES * 4);
  int* cursors  = (int*)alloc((size_t)2 * NB * 4);
  int* ce = cursors, *cv = cursors + NB;

  k_zero_cursors<<<1, 2 * NB, 0, stream>>>(cursors);
  k_bin<<<P1_BLOCKS, 256, 0, stream>>>(v_idx, e_idx, ce, cv, Te, Tv);
  k_sort<<<2 * NB + 32, 256, 0, stream>>>(ce, cv, Te, Tv, cnt_e, invde, starts_e,
                                          cnt_v, risv, starts_v, X, Xs, W, Wtp, Yeb);
  k_eg_gemm<<<N_EDGES / 16, 256, 0, stream>>>(Xs, risv, starts_e, cnt_e, Te, Wtp, bias, invde,
                                              (unsigned short*)Yeb);
  k_vertex_gather<<<(N_NODES / 4 + 3) / 4, 256, 0, stream>>>(Yeb, risv, starts_v, cnt_v, Tv, out);
}

// Round 10
// 262.516 us; speedup vs baseline: 1.2106x; 1.0217x over previous
//
#include <hip/hip_runtime.h>

#define N_NODES 100000
#define N_EDGES 20000
#define NNZ     1600000
#define D       128
#define DW      64                         // uints per bf16 row (2 ch per uint)
#define NSLICE  8
#define VSLICE  (N_NODES / NSLICE)         // 12500 vertices per slice (3.2 MB of Xs -> fits one XCD L2)

#define NB      256                        // buckets per side
#define CAP_E   8192
#define CAP_V   8192
#define SPAN_E  ((N_EDGES + NB - 1) / NB)  // 79
#define SPAN_V  ((N_NODES + NB - 1) / NB)  // 391
#define SP8     (SPAN_E * NSLICE)          // 632 sub-keys in edge sort
#define P1_CHUNK 8192
#define P1_ITER  (P1_CHUNK / 256)          // 32
#define P1_BLOCKS ((NNZ + P1_CHUNK - 1) / P1_CHUNK)  // 196

typedef __attribute__((ext_vector_type(8))) short bf16x8;
typedef __attribute__((ext_vector_type(4))) float f32x4;

__device__ __forceinline__ unsigned int pack_bf2(float lo, float hi) {
  unsigned int ul = __float_as_uint(lo), uh = __float_as_uint(hi);
  ul = (ul + 0x7FFFu + ((ul >> 16) & 1u)) >> 16;
  uh = (uh + 0x7FFFu + ((uh >> 16) & 1u)) & 0xFFFF0000u;
  return ul | uh;
}

// ---------------- zero bucket cursors ----------------
__global__ void k_zero_cursors(int* __restrict__ cur) {
  cur[threadIdx.x] = 0;                  // 512 = 2*NB
}

// ---------------- pass 1: bin incidences (cursors RELATIVE) ----------------
__global__ __launch_bounds__(256) void k_bin(const int* __restrict__ v_idx, const int* __restrict__ e_idx,
                                             int* __restrict__ ce, int* __restrict__ cv,
                                             unsigned int* __restrict__ Te, unsigned int* __restrict__ Tv) {
  __shared__ int he[NB], hv[NB], be[NB], bv[NB], le[NB], lv[NB];
  int t = threadIdx.x;
  he[t] = 0; hv[t] = 0; le[t] = 0; lv[t] = 0;
  __syncthreads();
  int base = blockIdx.x * P1_CHUNK;
  int v[P1_ITER], e[P1_ITER];
#pragma unroll
  for (int j = 0; j < P1_ITER; ++j) {
    int idx = base + j * 256 + t;
    if (idx < NNZ) {
      v[j] = v_idx[idx]; e[j] = e_idx[idx];
      atomicAdd(&he[e[j] / SPAN_E], 1);
      atomicAdd(&hv[v[j] / SPAN_V], 1);
    } else v[j] = -1;
  }
  __syncthreads();
  be[t] = he[t] ? atomicAdd(&ce[t], he[t]) : 0;
  bv[t] = hv[t] ? atomicAdd(&cv[t], hv[t]) : 0;
  __syncthreads();
#pragma unroll
  for (int j = 0; j < P1_ITER; ++j) {
    if (v[j] < 0) continue;
    int eb = e[j] / SPAN_E, vb = v[j] / SPAN_V;
    int se = be[eb] + atomicAdd(&le[eb], 1);
    int sv = bv[vb] + atomicAdd(&lv[vb], 1);
    if (se < CAP_E) Te[(size_t)eb * CAP_E + se] = ((unsigned)e[j] << 17) | (unsigned)v[j];
    if (sv < CAP_V) Tv[(size_t)vb * CAP_V + sv] = ((unsigned)v[j] << 15) | (unsigned)e[j];
  }
}

// ---------------- pass 2 merged: [0,NB) vertex (+prescale), [NB,2NB) edge (slice-subsorted), [2NB,+32) prep ----------------
__global__ __launch_bounds__(256) void k_sort(const int* __restrict__ ce, const int* __restrict__ cv,
                                              unsigned int* __restrict__ Te, unsigned int* __restrict__ Tv,
                                              int* __restrict__ cnt_e, float* __restrict__ invde,
                                              int* __restrict__ starts_e, uint2* __restrict__ cnt_es,
                                              int* __restrict__ cnt_v, float* __restrict__ risv,
                                              int* __restrict__ starts_v,
                                              const float* __restrict__ X, unsigned int* __restrict__ Xs,
                                              const float* __restrict__ W, unsigned int* __restrict__ Wtp,
                                              unsigned int* __restrict__ Yeb) {
  __shared__ unsigned int raw[CAP_V];
  __shared__ int hist[SP8], lcur[SP8], loff[SP8 + 1];
  __shared__ int sd[256];
  __shared__ float rv[SPAN_V];
  int t = threadIdx.x;
  if (blockIdx.x >= 2 * NB) {
    int bp = blockIdx.x - 2 * NB;
    if (bp == 0) {
      if (t < DW) { Xs[(size_t)N_NODES * DW + t] = 0u; Yeb[(size_t)N_EDGES * DW + t] = 0u; }
      if (t == 0) risv[N_NODES] = 0.f;
    }
    int idx = bp * 256 + t;
    if (idx < D * DW) {
      int c = idx & 127, kp = idx >> 7;
      float lo = W[(size_t)(2 * kp) * D + c];
      float hi = W[(size_t)(2 * kp + 1) * D + c];
      Wtp[c * DW + kp] = pack_bf2(lo, hi);
    }
    return;
  }
  if (blockIdx.x < NB) {
    int b = blockIdx.x;
    int v0 = b * SPAN_V;
    int span = N_NODES - v0; if (span > SPAN_V) span = SPAN_V;
    if (span <= 0) return;
    int n = cv[b]; if (n > CAP_V) n = CAP_V; if (n < 0) n = 0;
    for (int i = t; i < n; i += 256) raw[i] = Tv[(size_t)b * CAP_V + i];
    for (int i = t; i < span; i += 256) { hist[i] = 0; lcur[i] = 0; }
    __syncthreads();
    for (int i = t; i < n; i += 256) atomicAdd(&hist[(int)(raw[i] >> 15) - v0], 1);
    __syncthreads();
    {  // parallel exclusive scan (2/thread covers 391)
      int i0 = 2 * t, i1 = 2 * t + 1;
      int s0 = (i0 < span) ? hist[i0] : 0;
      int s1 = (i1 < span) ? hist[i1] : 0;
      int mysum = s0 + s1;
      sd[t] = mysum; __syncthreads();
      for (int off = 1; off < 256; off <<= 1) {
        int add = (t >= off) ? sd[t - off] : 0;
        __syncthreads(); sd[t] += add; __syncthreads();
      }
      int bse = sd[t] - mysum;
      if (i0 < span) loff[i0] = bse;
      if (i1 < span) loff[i1] = bse + s0;
      __syncthreads();
    }
    for (int i = t; i < n; i += 256) {
      unsigned int p = raw[i];
      int l = (int)(p >> 15) - v0;
      int slot = loff[l] + atomicAdd(&lcur[l], 1);
      Tv[(size_t)b * CAP_V + slot] = p & 0x7FFFu;
    }
    for (int i = t; i < span; i += 256) {
      int d = hist[i];
      float r = d > 0 ? rsqrtf((float)d) : 0.0f;
      cnt_v[v0 + i] = d;
      risv[v0 + i] = r;
      rv[i] = r;
      starts_v[v0 + i] = b * CAP_V + loff[i];
    }
    __syncthreads();
    int total = span * DW;
    for (int idx = t; idx < total; idx += 256) {
      int vl = idx >> 6;
      float r = rv[vl];
      size_t gp = (size_t)(v0 + vl) * DW + (idx & 63);
      float2 x = *(const float2*)(X + gp * 2);
      Xs[gp] = pack_bf2(r * x.x, r * x.y);
    }
  } else {
    int b = blockIdx.x - NB;
    int e0 = b * SPAN_E;
    int span = N_EDGES - e0; if (span > SPAN_E) span = SPAN_E;
    if (span <= 0) return;
    int sp8 = span * NSLICE;
    int n = ce[b]; if (n > CAP_E) n = CAP_E; if (n < 0) n = 0;
    for (int i = t; i < n; i += 256) raw[i] = Te[(size_t)b * CAP_E + i];
    for (int i = t; i < sp8; i += 256) { hist[i] = 0; lcur[i] = 0; }
    __syncthreads();
    for (int i = t; i < n; i += 256) {
      unsigned int p = raw[i];
      int l = (int)(p >> 17) - e0;
      int s = (int)(p & 0x1FFFFu) / VSLICE;
      atomicAdd(&hist[l * NSLICE + s], 1);
    }
    __syncthreads();
    {  // parallel exclusive scan over sp8 (3/thread covers 632)
      int i0 = 3 * t;
      int s0 = (i0 < sp8) ? hist[i0] : 0;
      int s1 = (i0 + 1 < sp8) ? hist[i0 + 1] : 0;
      int s2 = (i0 + 2 < sp8) ? hist[i0 + 2] : 0;
      int mysum = s0 + s1 + s2;
      sd[t] = mysum; __syncthreads();
      for (int off = 1; off < 256; off <<= 1) {
        int add = (t >= off) ? sd[t - off] : 0;
        __syncthreads(); sd[t] += add; __syncthreads();
      }
      int bse = sd[t] - mysum;
      if (i0 < sp8)     loff[i0]     = bse;
      if (i0 + 1 < sp8) loff[i0 + 1] = bse + s0;
      if (i0 + 2 < sp8) loff[i0 + 2] = bse + s0 + s1;
      __syncthreads();
    }
    for (int i = t; i < n; i += 256) {
      unsigned int p = raw[i];
      int l = (int)(p >> 17) - e0;
      unsigned v = p & 0x1FFFFu;
      int k2 = l * NSLICE + (int)v / VSLICE;
      int slot = loff[k2] + atomicAdd(&lcur[k2], 1);
      Te[(size_t)b * CAP_E + slot] = v;
    }
    for (int i = t; i < span; i += 256) {
      int c0 = hist[i*8+0], c1 = hist[i*8+1], c2 = hist[i*8+2], c3 = hist[i*8+3];
      int c4 = hist[i*8+4], c5 = hist[i*8+5], c6 = hist[i*8+6], c7 = hist[i*8+7];
      int d = c0+c1+c2+c3+c4+c5+c6+c7;
      cnt_e[e0 + i] = d;
      invde[e0 + i] = d > 0 ? 1.0f / (float)d : 0.0f;
      starts_e[e0 + i] = b * CAP_E + loff[i * NSLICE];
      cnt_es[e0 + i] = make_uint2((unsigned)(c0|(c1<<8)|(c2<<16)|(c3<<24)),
                                  (unsigned)(c4|(c5<<8)|(c6<<16)|(c7<<24)));
    }
  }
}

// ---------------- pass A (sliced): partial Qp[e][slice] = bf16(sum over slice members), qp = sum risv ----------------
// slice = blockIdx%8 -> XCD round-robin pins each slice to one XCD; Xs slice (3.2 MB) stays L2-local.
__global__ __launch_bounds__(256) void k_egA(const unsigned int* __restrict__ Xs, const float* __restrict__ risv,
                                             const int* __restrict__ starts_e, const uint2* __restrict__ cnt_es,
                                             const unsigned int* __restrict__ members,
                                             unsigned int* __restrict__ Qp, float* __restrict__ qp) {
  int slice = blockIdx.x & 7;
  int grp = blockIdx.x >> 3;
  int tid = threadIdx.x;
  int wv = tid >> 6, lane = tid & 63;
  int g = lane >> 4, l16 = lane & 15;
  int row = wv * 4 + g;
  int e = grp * 16 + row;                 // grid exact: 1250*16 = 20000
  uint2 cs = cnt_es[e];
  int c[8];
  c[0]=cs.x&255; c[1]=(cs.x>>8)&255; c[2]=(cs.x>>16)&255; c[3]=(cs.x>>24)&255;
  c[4]=cs.y&255; c[5]=(cs.y>>8)&255; c[6]=(cs.y>>16)&255; c[7]=(cs.y>>24)&255;
  int pre = 0;
  for (int s = 0; s < slice; ++s) pre += c[s];   // slice is block-uniform
  int len = c[slice];
  int beg = starts_e[e] + pre;
  int maxc = len;
  maxc = max(maxc, __shfl_xor(maxc, 16));
  maxc = max(maxc, __shfl_xor(maxc, 32));
  float a0=0,a1=0,a2=0,a3=0,a4=0,a5=0,a6=0,a7=0,q=0.f;
  for (int i = 0; i < maxc; i += 4) {
    int vv[4];
#pragma unroll
    for (int j = 0; j < 4; ++j) {
      int idx = i + j;
      int m = (int)members[beg + idx];    // slack stays inside padded ws
      vv[j] = (idx < len) ? m : N_NODES;  // dummy zero row
    }
    uint4 xx[4];
#pragma unroll
    for (int j = 0; j < 4; ++j) xx[j] = *(const uint4*)(Xs + (size_t)vv[j] * DW + l16 * 4);
#pragma unroll
    for (int j = 0; j < 4; ++j) q += risv[vv[j]];
#pragma unroll
    for (int j = 0; j < 4; ++j) {
      a0 += __uint_as_float(xx[j].x << 16); a1 += __uint_as_float(xx[j].x & 0xFFFF0000u);
      a2 += __uint_as_float(xx[j].y << 16); a3 += __uint_as_float(xx[j].y & 0xFFFF0000u);
      a4 += __uint_as_float(xx[j].z << 16); a5 += __uint_as_float(xx[j].z & 0xFFFF0000u);
      a6 += __uint_as_float(xx[j].w << 16); a7 += __uint_as_float(xx[j].w & 0xFFFF0000u);
    }
  }
  uint4 o;
  o.x = pack_bf2(a0, a1); o.y = pack_bf2(a2, a3);
  o.z = pack_bf2(a4, a5); o.w = pack_bf2(a6, a7);
  *(uint4*)(Qp + ((size_t)e * NSLICE + slice) * DW + l16 * 4) = o;
  if (l16 == 0) qp[(size_t)e * NSLICE + slice] = q;
}

// ---------------- GEMM with partial combine: Yeb[e] = bf16(invde*(sum_s Qp[e][s] @ W + qv*b)) ----------------
__global__ __launch_bounds__(256) void k_gemm2(const unsigned int* __restrict__ Qp, const float* __restrict__ qp,
                                               const unsigned int* __restrict__ Wtp, const float* __restrict__ bias,
                                               const float* __restrict__ invde, unsigned short* __restrict__ Yeb) {
  __shared__ unsigned int Qls[16][DW];
  __shared__ float qls[16], ivls[16];
  int tid = threadIdx.x;
  int wv = tid >> 6, lane = tid & 63;
  int g = lane >> 4, l16 = lane & 15;
  int row = wv * 4 + g;
  int e = blockIdx.x * 16 + row;
  float a0=0,a1=0,a2=0,a3=0,a4=0,a5=0,a6=0,a7=0;
#pragma unroll
  for (int s = 0; s < NSLICE; ++s) {
    uint4 x = *(const uint4*)(Qp + ((size_t)e * NSLICE + s) * DW + l16 * 4);
    a0 += __uint_as_float(x.x << 16); a1 += __uint_as_float(x.x & 0xFFFF0000u);
    a2 += __uint_as_float(x.y << 16); a3 += __uint_as_float(x.y & 0xFFFF0000u);
    a4 += __uint_as_float(x.z << 16); a5 += __uint_as_float(x.z & 0xFFFF0000u);
    a6 += __uint_as_float(x.w << 16); a7 += __uint_as_float(x.w & 0xFFFF0000u);
  }
  uint4 o;
  o.x = pack_bf2(a0, a1); o.y = pack_bf2(a2, a3);
  o.z = pack_bf2(a4, a5); o.w = pack_bf2(a6, a7);
  *(uint4*)&Qls[row][(l16 ^ row) * 4] = o;
  if (l16 == 0) {
    float q = 0.f;
#pragma unroll
    for (int s = 0; s < NSLICE; ++s) q += qp[(size_t)e * NSLICE + s];
    qls[row] = q; ivls[row] = invde[e];
  }
  __syncthreads();
  f32x4 acc[2];
  acc[0] = (f32x4){0.f,0.f,0.f,0.f}; acc[1] = (f32x4){0.f,0.f,0.f,0.f};
#pragma unroll
  for (int kt = 0; kt < 4; ++kt) {
    int s = kt * 4 + g;
    bf16x8 a = *(const bf16x8*)&Qls[l16][(s ^ l16) * 4];
#pragma unroll
    for (int n = 0; n < 2; ++n) {
      int nt = wv * 2 + n;
      bf16x8 b = *(const bf16x8*)(Wtp + (size_t)(nt * 16 + l16) * DW + kt * 16 + g * 4);
      acc[n] = __builtin_amdgcn_mfma_f32_16x16x32_bf16(a, b, acc[n], 0, 0, 0);
    }
  }
#pragma unroll
  for (int r = 0; r < 4; ++r) {
    int lrow = g * 4 + r;
    int erow = blockIdx.x * 16 + lrow;
    float s = ivls[lrow], qq = qls[lrow];
#pragma unroll
    for (int n = 0; n < 2; ++n) {
      int cc = (wv * 2 + n) * 16 + l16;
      float val = s * (acc[n][r] + qq * bias[cc]);
      unsigned int u = __float_as_uint(val);
      u = (u + 0x7FFFu + ((u >> 16) & 1u)) >> 16;
      Yeb[(size_t)erow * D + cc] = (unsigned short)u;
    }
  }
}

// ---------------- fallback: R9's fused gather+GEMM (used when ws too small for Qp) ----------------
__global__ __launch_bounds__(256) void k_eg_gemm(const unsigned int* __restrict__ Xs, const float* __restrict__ risv,
                                                 const int* __restrict__ starts_e, const int* __restrict__ cnt_e,
                                                 const unsigned int* __restrict__ members,
                                                 const unsigned int* __restrict__ Wtp, const float* __restrict__ bias,
                                                 const float* __restrict__ invde, unsigned short* __restrict__ Yeb) {
  __shared__ unsigned int Qls[16][DW];
  __shared__ float qls[16], ivls[16];
  int tid = threadIdx.x;
  int wv = tid >> 6, lane = tid & 63;
  int g = lane >> 4, l16 = lane & 15;
  int row = wv * 4 + g;
  int e = blockIdx.x * 16 + row;
  int beg = starts_e[e];
  int cnt = cnt_e[e];
  int maxc = cnt;
  maxc = max(maxc, __shfl_xor(maxc, 16));
  maxc = max(maxc, __shfl_xor(maxc, 32));
  float a0=0,a1=0,a2=0,a3=0,a4=0,a5=0,a6=0,a7=0,q=0.f;
  for (int i = 0; i < maxc; i += 8) {
    int vv[8];
#pragma unroll
    for (int j = 0; j < 8; ++j) {
      int idx = i + j;
      int m = (int)members[beg + idx];
      vv[j] = (idx < cnt) ? m : N_NODES;
    }
    uint4 xx[8];
#pragma unroll
    for (int j = 0; j < 8; ++j) xx[j] = *(const uint4*)(Xs + (size_t)vv[j] * DW + l16 * 4);
#pragma unroll
    for (int j = 0; j < 8; ++j) q += risv[vv[j]];
#pragma unroll
    for (int j = 0; j < 8; ++j) {
      a0 += __uint_as_float(xx[j].x << 16); a1 += __uint_as_float(xx[j].x & 0xFFFF0000u);
      a2 += __uint_as_float(xx[j].y << 16); a3 += __uint_as_float(xx[j].y & 0xFFFF0000u);
      a4 += __uint_as_float(xx[j].z << 16); a5 += __uint_as_float(xx[j].z & 0xFFFF0000u);
      a6 += __uint_as_float(xx[j].w << 16); a7 += __uint_as_float(xx[j].w & 0xFFFF0000u);
    }
  }
  uint4 o;
  o.x = pack_bf2(a0, a1); o.y = pack_bf2(a2, a3);
  o.z = pack_bf2(a4, a5); o.w = pack_bf2(a6, a7);
  *(uint4*)&Qls[row][(l16 ^ row) * 4] = o;
  if (l16 == 0) { qls[row] = q; ivls[row] = invde[e]; }
  __syncthreads();
  f32x4 acc[2];
  acc[0] = (f32x4){0.f,0.f,0.f,0.f}; acc[1] = (f32x4){0.f,0.f,0.f,0.f};
#pragma unroll
  for (int kt = 0; kt < 4; ++kt) {
    int s = kt * 4 + g;
    bf16x8 a = *(const bf16x8*)&Qls[l16][(s ^ l16) * 4];
#pragma unroll
    for (int n = 0; n < 2; ++n) {
      int nt = wv * 2 + n;
      bf16x8 b = *(const bf16x8*)(Wtp + (size_t)(nt * 16 + l16) * DW + kt * 16 + g * 4);
      acc[n] = __builtin_amdgcn_mfma_f32_16x16x32_bf16(a, b, acc[n], 0, 0, 0);
    }
  }
#pragma unroll
  for (int r = 0; r < 4; ++r) {
    int lrow = g * 4 + r;
    int erow = blockIdx.x * 16 + lrow;
    float s = ivls[lrow], qq = qls[lrow];
#pragma unroll
    for (int n = 0; n < 2; ++n) {
      int cc = (wv * 2 + n) * 16 + l16;
      float val = s * (acc[n][r] + qq * bias[cc]);
      unsigned int u = __float_as_uint(val);
      u = (u + 0x7FFFu + ((u >> 16) & 1u)) >> 16;
      Yeb[(size_t)erow * D + cc] = (unsigned short)u;
    }
  }
}

// ---------------- phase B: 4 vertices per wave, 16 lanes x uint4 per row ----------------
__global__ __launch_bounds__(256) void k_vertex_gather(const unsigned int* __restrict__ Yeb, const float* __restrict__ risv,
                                const int* __restrict__ starts_v, const int* __restrict__ cnt_v,
                                const unsigned int* __restrict__ members,
                                float* __restrict__ out) {
  int wv = (blockIdx.x * 256 + threadIdx.x) >> 6;
  int lane = threadIdx.x & 63;
  int g = lane >> 4, l16 = lane & 15;
  int v = wv * 4 + g;
  if (v >= N_NODES) return;
  int beg = starts_v[v];
  int cnt = cnt_v[v];
  int maxc = cnt;
  maxc = max(maxc, __shfl_xor(maxc, 16));
  maxc = max(maxc, __shfl_xor(maxc, 32));
  float a0=0,a1=0,a2=0,a3=0,a4=0,a5=0,a6=0,a7=0;
  for (int i = 0; i < maxc; i += 8) {
    int ee[8];
#pragma unroll
    for (int j = 0; j < 8; ++j) {
      int idx = i + j;
      int m = (int)members[beg + idx];
      ee[j] = (idx < cnt) ? m : N_EDGES;
    }
    uint4 yy[8];
#pragma unroll
    for (int j = 0; j < 8; ++j) yy[j] = *(const uint4*)(Yeb + (size_t)ee[j] * DW + l16 * 4);
#pragma unroll
    for (int j = 0; j < 8; ++j) {
      a0 += __uint_as_float(yy[j].x << 16); a1 += __uint_as_float(yy[j].x & 0xFFFF0000u);
      a2 += __uint_as_float(yy[j].y << 16); a3 += __uint_as_float(yy[j].y & 0xFFFF0000u);
      a4 += __uint_as_float(yy[j].z << 16); a5 += __uint_as_float(yy[j].z & 0xFFFF0000u);
      a6 += __uint_as_float(yy[j].w << 16); a7 += __uint_as_float(yy[j].w & 0xFFFF0000u);
    }
  }
  float s = risv[v];
  float4 o0, o1;
  o0.x = fmaxf(a0 * s, 0.f); o0.y = fmaxf(a1 * s, 0.f);
  o0.z = fmaxf(a2 * s, 0.f); o0.w = fmaxf(a3 * s, 0.f);
  o1.x = fmaxf(a4 * s, 0.f); o1.y = fmaxf(a5 * s, 0.f);
  o1.z = fmaxf(a6 * s, 0.f); o1.w = fmaxf(a7 * s, 0.f);
  float* orow = out + (size_t)v * D + l16 * 8;
  *(float4*)orow = o0;
  *(float4*)(orow + 4) = o1;
}

extern "C" void kernel_launch(void* const* d_in, const int* in_sizes, int n_in,
                              void* d_out, int out_size, void* d_ws, size_t ws_size,
                              hipStream_t stream) {
  const float* X    = (const float*)d_in[0];
  const float* W    = (const float*)d_in[1];
  const float* bias = (const float*)d_in[2];
  const int* v_idx  = (const int*)d_in[3];
  const int* e_idx  = (const int*)d_in[4];
  float* out = (float*)d_out;

  char* p = (char*)d_ws;
  auto alloc = [&](size_t bytes) { char* r = p; p += (bytes + 255) & ~(size_t)255; return r; };
  unsigned int* Te  = (unsigned int*)alloc(((size_t)NB + 1) * CAP_E * 4);   // +1 bucket slack pad
  unsigned int* Tv  = (unsigned int*)alloc(((size_t)NB + 1) * CAP_V * 4);
  unsigned int* Xs  = (unsigned int*)alloc((size_t)(N_NODES + 1) * DW * 4);
  unsigned int* Yeb = (unsigned int*)alloc((size_t)(N_EDGES + 1) * DW * 4);
  unsigned int* Wtp = (unsigned int*)alloc((size_t)D * DW * 4);
  float* risv  = (float*)alloc((size_t)(N_NODES + 1) * 4);
  float* invde = (float*)alloc((size_t)N_EDGES * 4);
  int* cnt_e    = (int*)alloc((size_t)N_EDGES * 4);
  uint2* cnt_es = (uint2*)alloc((size_t)N_EDGES * 8);
  int* cnt_v    = (int*)alloc((size_t)N_NODES * 4);
  int* starts_e = (int*)alloc((size_t)N_EDGES * 4);
  int* starts_v = (int*)alloc((size_t)N_NODES * 4);
  int* cursors  = (int*)alloc((size_t)2 * NB * 4);
  int* ce = cursors, *cv = cursors + NB;
  // sliced-path scratch last, gated on ws_size
  unsigned int* Qp = (unsigned int*)alloc((size_t)N_EDGES * NSLICE * DW * 4);  // 41 MB
  float* qp        = (float*)alloc((size_t)N_EDGES * NSLICE * 4);
  size_t need = (size_t)(p - (char*)d_ws);
  bool sliced = ws_size >= need;

  k_zero_cursors<<<1, 2 * NB, 0, stream>>>(cursors);
  k_bin<<<P1_BLOCKS, 256, 0, stream>>>(v_idx, e_idx, ce, cv, Te, Tv);
  k_sort<<<2 * NB + 32, 256, 0, stream>>>(ce, cv, Te, Tv, cnt_e, invde, starts_e, cnt_es,
                                          cnt_v, risv, starts_v, X, Xs, W, Wtp, Yeb);
  if (sliced) {
    k_egA<<<NSLICE * (N_EDGES / 16), 256, 0, stream>>>(Xs, risv, starts_e, cnt_es, Te, Qp, qp);
    k_gemm2<<<N_EDGES / 16, 256, 0, stream>>>(Qp, qp, Wtp, bias, invde, (unsigned short*)Yeb);
  } else {
    k_eg_gemm<<<N_EDGES / 16, 256, 0, stream>>>(Xs, risv, starts_e, cnt_e, Te, Wtp, bias, invde,
                                                (unsigned short*)Yeb);
  }
  k_vertex_gather<<<(N_NODES / 4 + 3) / 4, 256, 0, stream>>>(Yeb, risv, starts_v, cnt_v, Tv, out);
}

// Round 11
// 258.076 us; speedup vs baseline: 1.2314x; 1.0172x over previous
//
#include <hip/hip_runtime.h>

#define N_NODES 100000
#define N_EDGES 20000
#define NNZ     1600000
#define D       128
#define DW      64                         // uints per bf16 row (2 ch per uint)
#define NSLICE  8
#define VSLICE  (N_NODES / NSLICE)         // 12500 vertices/slice (3.2 MB Xs -> one XCD L2)

#define NB      512                        // buckets per side (R11: 256->512 for occupancy)
#define CAP_E   4096
#define CAP_V   4096
#define SPAN_E  ((N_EDGES + NB - 1) / NB)  // 40
#define SPAN_V  ((N_NODES + NB - 1) / NB)  // 196
#define SP8     (SPAN_E * NSLICE)          // 320 sub-keys in edge sort
#define P1_CHUNK 8192
#define P1_ITER  (P1_CHUNK / 256)          // 32
#define P1_BLOCKS ((NNZ + P1_CHUNK - 1) / P1_CHUNK)  // 196

typedef __attribute__((ext_vector_type(8))) short bf16x8;
typedef __attribute__((ext_vector_type(4))) float f32x4;

__device__ __forceinline__ unsigned int pack_bf2(float lo, float hi) {
  unsigned int ul = __float_as_uint(lo), uh = __float_as_uint(hi);
  ul = (ul + 0x7FFFu + ((ul >> 16) & 1u)) >> 16;
  uh = (uh + 0x7FFFu + ((uh >> 16) & 1u)) & 0xFFFF0000u;
  return ul | uh;
}

// ---------------- zero bucket cursors ----------------
__global__ void k_zero_cursors(int* __restrict__ cur) {
  cur[threadIdx.x] = 0;                  // 1024 = 2*NB
}

// ---------------- pass 1: bin incidences (cursors RELATIVE) ----------------
__global__ __launch_bounds__(256) void k_bin(const int* __restrict__ v_idx, const int* __restrict__ e_idx,
                                             int* __restrict__ ce, int* __restrict__ cv,
                                             unsigned int* __restrict__ Te, unsigned int* __restrict__ Tv) {
  __shared__ int he[NB], hv[NB], be[NB], bv[NB], le[NB], lv[NB];
  int t = threadIdx.x;
#pragma unroll
  for (int b = 0; b < NB; b += 256) { he[b + t] = 0; hv[b + t] = 0; le[b + t] = 0; lv[b + t] = 0; }
  __syncthreads();
  int base = blockIdx.x * P1_CHUNK;
  int v[P1_ITER], e[P1_ITER];
#pragma unroll
  for (int j = 0; j < P1_ITER; ++j) {
    int idx = base + j * 256 + t;
    if (idx < NNZ) {
      v[j] = v_idx[idx]; e[j] = e_idx[idx];
      atomicAdd(&he[e[j] / SPAN_E], 1);
      atomicAdd(&hv[v[j] / SPAN_V], 1);
    } else v[j] = -1;
  }
  __syncthreads();
#pragma unroll
  for (int b = 0; b < NB; b += 256) {
    be[b + t] = he[b + t] ? atomicAdd(&ce[b + t], he[b + t]) : 0;
    bv[b + t] = hv[b + t] ? atomicAdd(&cv[b + t], hv[b + t]) : 0;
  }
  __syncthreads();
#pragma unroll
  for (int j = 0; j < P1_ITER; ++j) {
    if (v[j] < 0) continue;
    int eb = e[j] / SPAN_E, vb = v[j] / SPAN_V;
    int se = be[eb] + atomicAdd(&le[eb], 1);
    int sv = bv[vb] + atomicAdd(&lv[vb], 1);
    if (se < CAP_E) Te[(size_t)eb * CAP_E + se] = ((unsigned)e[j] << 17) | (unsigned)v[j];
    if (sv < CAP_V) Tv[(size_t)vb * CAP_V + sv] = ((unsigned)v[j] << 15) | (unsigned)e[j];
  }
}

// ---------------- pass 2 merged: [0,NB) vertex (+prescale), [NB,2NB) edge (slice-subsorted), [2NB,+32) prep ----------------
__global__ __launch_bounds__(256) void k_sort(const int* __restrict__ ce, const int* __restrict__ cv,
                                              unsigned int* __restrict__ Te, unsigned int* __restrict__ Tv,
                                              int* __restrict__ cnt_e, float* __restrict__ invde,
                                              int* __restrict__ starts_e, uint2* __restrict__ cnt_es,
                                              int* __restrict__ cnt_v, float* __restrict__ risv,
                                              int* __restrict__ starts_v,
                                              const float* __restrict__ X, unsigned int* __restrict__ Xs,
                                              const float* __restrict__ W, unsigned int* __restrict__ Wtp,
                                              unsigned int* __restrict__ Yeb) {
  __shared__ unsigned int raw[CAP_V];
  __shared__ int hist[SP8], lcur[SP8], loff[SP8 + 1];
  __shared__ int sd[256];
  __shared__ float rv[SPAN_V];
  int t = threadIdx.x;
  if (blockIdx.x >= 2 * NB) {
    int bp = blockIdx.x - 2 * NB;
    if (bp == 0) {
      if (t < DW) { Xs[(size_t)N_NODES * DW + t] = 0u; Yeb[(size_t)N_EDGES * DW + t] = 0u; }
      if (t == 0) risv[N_NODES] = 0.f;
    }
    int idx = bp * 256 + t;
    if (idx < D * DW) {
      int c = idx & 127, kp = idx >> 7;
      float lo = W[(size_t)(2 * kp) * D + c];
      float hi = W[(size_t)(2 * kp + 1) * D + c];
      Wtp[c * DW + kp] = pack_bf2(lo, hi);
    }
    return;
  }
  if (blockIdx.x < NB) {
    int b = blockIdx.x;
    int v0 = b * SPAN_V;
    int span = N_NODES - v0; if (span > SPAN_V) span = SPAN_V;
    if (span <= 0) return;
    int n = cv[b]; if (n > CAP_V) n = CAP_V; if (n < 0) n = 0;
    for (int i = t; i < n; i += 256) raw[i] = Tv[(size_t)b * CAP_V + i];
    for (int i = t; i < span; i += 256) { hist[i] = 0; lcur[i] = 0; }
    __syncthreads();
    for (int i = t; i < n; i += 256) atomicAdd(&hist[(int)(raw[i] >> 15) - v0], 1);
    __syncthreads();
    {  // parallel exclusive scan; span<=196<=256 -> 1/thread
      int s0 = (t < span) ? hist[t] : 0;
      int mysum = s0;
      sd[t] = mysum; __syncthreads();
      for (int off = 1; off < 256; off <<= 1) {
        int add = (t >= off) ? sd[t - off] : 0;
        __syncthreads(); sd[t] += add; __syncthreads();
      }
      int bse = sd[t] - mysum;
      if (t < span) loff[t] = bse;
      __syncthreads();
    }
    for (int i = t; i < n; i += 256) {
      unsigned int p = raw[i];
      int l = (int)(p >> 15) - v0;
      int slot = loff[l] + atomicAdd(&lcur[l], 1);
      Tv[(size_t)b * CAP_V + slot] = p & 0x7FFFu;
    }
    for (int i = t; i < span; i += 256) {
      int d = hist[i];
      float r = d > 0 ? rsqrtf((float)d) : 0.0f;
      cnt_v[v0 + i] = d;
      risv[v0 + i] = r;
      rv[i] = r;
      starts_v[v0 + i] = b * CAP_V + loff[i];
    }
    __syncthreads();
    // fused prescale: Xs[v] = bf16(risv[v] * X[v])
    int total = span * DW;
    for (int idx = t; idx < total; idx += 256) {
      int vl = idx >> 6;
      float r = rv[vl];
      size_t gp = (size_t)(v0 + vl) * DW + (idx & 63);
      float2 x = *(const float2*)(X + gp * 2);
      Xs[gp] = pack_bf2(r * x.x, r * x.y);
    }
  } else {
    int b = blockIdx.x - NB;
    int e0 = b * SPAN_E;
    int span = N_EDGES - e0; if (span > SPAN_E) span = SPAN_E;
    if (span <= 0) return;
    int sp8 = span * NSLICE;
    int n = ce[b]; if (n > CAP_E) n = CAP_E; if (n < 0) n = 0;
    for (int i = t; i < n; i += 256) raw[i] = Te[(size_t)b * CAP_E + i];
    for (int i = t; i < sp8; i += 256) { hist[i] = 0; lcur[i] = 0; }
    __syncthreads();
    for (int i = t; i < n; i += 256) {
      unsigned int p = raw[i];
      int l = (int)(p >> 17) - e0;
      int s = (int)(p & 0x1FFFFu) / VSLICE;
      atomicAdd(&hist[l * NSLICE + s], 1);
    }
    __syncthreads();
    {  // parallel exclusive scan over sp8<=320 -> 2/thread
      int i0 = 2 * t, i1 = 2 * t + 1;
      int s0 = (i0 < sp8) ? hist[i0] : 0;
      int s1 = (i1 < sp8) ? hist[i1] : 0;
      int mysum = s0 + s1;
      sd[t] = mysum; __syncthreads();
      for (int off = 1; off < 256; off <<= 1) {
        int add = (t >= off) ? sd[t - off] : 0;
        __syncthreads(); sd[t] += add; __syncthreads();
      }
      int bse = sd[t] - mysum;
      if (i0 < sp8) loff[i0] = bse;
      if (i1 < sp8) loff[i1] = bse + s0;
      __syncthreads();
    }
    for (int i = t; i < n; i += 256) {
      unsigned int p = raw[i];
      int l = (int)(p >> 17) - e0;
      unsigned v = p & 0x1FFFFu;
      int k2 = l * NSLICE + (int)v / VSLICE;
      int slot = loff[k2] + atomicAdd(&lcur[k2], 1);
      Te[(size_t)b * CAP_E + slot] = v;
    }
    for (int i = t; i < span; i += 256) {
      int c0 = hist[i*8+0], c1 = hist[i*8+1], c2 = hist[i*8+2], c3 = hist[i*8+3];
      int c4 = hist[i*8+4], c5 = hist[i*8+5], c6 = hist[i*8+6], c7 = hist[i*8+7];
      int d = c0+c1+c2+c3+c4+c5+c6+c7;
      cnt_e[e0 + i] = d;
      invde[e0 + i] = d > 0 ? 1.0f / (float)d : 0.0f;
      starts_e[e0 + i] = b * CAP_E + loff[i * NSLICE];
      cnt_es[e0 + i] = make_uint2((unsigned)(c0|(c1<<8)|(c2<<16)|(c3<<24)),
                                  (unsigned)(c4|(c5<<8)|(c6<<16)|(c7<<24)));
    }
  }
}

// ---------------- pass A (sliced): partial Qp[e][slice]; slice = blockIdx%8 -> XCD-local Xs ----------------
__global__ __launch_bounds__(256) void k_egA(const unsigned int* __restrict__ Xs, const float* __restrict__ risv,
                                             const int* __restrict__ starts_e, const uint2* __restrict__ cnt_es,
                                             const unsigned int* __restrict__ members,
                                             unsigned int* __restrict__ Qp, float* __restrict__ qp) {
  int slice = blockIdx.x & 7;
  int grp = blockIdx.x >> 3;
  int tid = threadIdx.x;
  int wv = tid >> 6, lane = tid & 63;
  int g = lane >> 4, l16 = lane & 15;
  int row = wv * 4 + g;
  int e = grp * 16 + row;                 // grid exact: 1250*16 = 20000
  uint2 cs = cnt_es[e];
  int c[8];
  c[0]=cs.x&255; c[1]=(cs.x>>8)&255; c[2]=(cs.x>>16)&255; c[3]=(cs.x>>24)&255;
  c[4]=cs.y&255; c[5]=(cs.y>>8)&255; c[6]=(cs.y>>16)&255; c[7]=(cs.y>>24)&255;
  int pre = 0;
  for (int s = 0; s < slice; ++s) pre += c[s];   // slice is block-uniform
  int len = c[slice];
  int beg = starts_e[e] + pre;
  int maxc = len;
  maxc = max(maxc, __shfl_xor(maxc, 16));
  maxc = max(maxc, __shfl_xor(maxc, 32));
  float a0=0,a1=0,a2=0,a3=0,a4=0,a5=0,a6=0,a7=0,q=0.f;
  for (int i = 0; i < maxc; i += 4) {
    int vv[4];
#pragma unroll
    for (int j = 0; j < 4; ++j) {
      int idx = i + j;
      int m = (int)members[beg + idx];    // slack stays inside padded ws
      vv[j] = (idx < len) ? m : N_NODES;  // dummy zero row
    }
    uint4 xx[4];
#pragma unroll
    for (int j = 0; j < 4; ++j) xx[j] = *(const uint4*)(Xs + (size_t)vv[j] * DW + l16 * 4);
#pragma unroll
    for (int j = 0; j < 4; ++j) q += risv[vv[j]];
#pragma unroll
    for (int j = 0; j < 4; ++j) {
      a0 += __uint_as_float(xx[j].x << 16); a1 += __uint_as_float(xx[j].x & 0xFFFF0000u);
      a2 += __uint_as_float(xx[j].y << 16); a3 += __uint_as_float(xx[j].y & 0xFFFF0000u);
      a4 += __uint_as_float(xx[j].z << 16); a5 += __uint_as_float(xx[j].z & 0xFFFF0000u);
      a6 += __uint_as_float(xx[j].w << 16); a7 += __uint_as_float(xx[j].w & 0xFFFF0000u);
    }
  }
  uint4 o;
  o.x = pack_bf2(a0, a1); o.y = pack_bf2(a2, a3);
  o.z = pack_bf2(a4, a5); o.w = pack_bf2(a6, a7);
  *(uint4*)(Qp + ((size_t)e * NSLICE + slice) * DW + l16 * 4) = o;
  if (l16 == 0) qp[(size_t)e * NSLICE + slice] = q;
}

// ---------------- GEMM with partial combine ----------------
__global__ __launch_bounds__(256) void k_gemm2(const unsigned int* __restrict__ Qp, const float* __restrict__ qp,
                                               const unsigned int* __restrict__ Wtp, const float* __restrict__ bias,
                                               const float* __restrict__ invde, unsigned short* __restrict__ Yeb) {
  __shared__ unsigned int Qls[16][DW];
  __shared__ float qls[16], ivls[16];
  int tid = threadIdx.x;
  int wv = tid >> 6, lane = tid & 63;
  int g = lane >> 4, l16 = lane & 15;
  int row = wv * 4 + g;
  int e = blockIdx.x * 16 + row;
  float a0=0,a1=0,a2=0,a3=0,a4=0,a5=0,a6=0,a7=0;
#pragma unroll
  for (int s = 0; s < NSLICE; ++s) {
    uint4 x = *(const uint4*)(Qp + ((size_t)e * NSLICE + s) * DW + l16 * 4);
    a0 += __uint_as_float(x.x << 16); a1 += __uint_as_float(x.x & 0xFFFF0000u);
    a2 += __uint_as_float(x.y << 16); a3 += __uint_as_float(x.y & 0xFFFF0000u);
    a4 += __uint_as_float(x.z << 16); a5 += __uint_as_float(x.z & 0xFFFF0000u);
    a6 += __uint_as_float(x.w << 16); a7 += __uint_as_float(x.w & 0xFFFF0000u);
  }
  uint4 o;
  o.x = pack_bf2(a0, a1); o.y = pack_bf2(a2, a3);
  o.z = pack_bf2(a4, a5); o.w = pack_bf2(a6, a7);
  *(uint4*)&Qls[row][(l16 ^ row) * 4] = o;
  if (l16 == 0) {
    float q = 0.f;
#pragma unroll
    for (int s = 0; s < NSLICE; ++s) q += qp[(size_t)e * NSLICE + s];
    qls[row] = q; ivls[row] = invde[e];
  }
  __syncthreads();
  f32x4 acc[2];
  acc[0] = (f32x4){0.f,0.f,0.f,0.f}; acc[1] = (f32x4){0.f,0.f,0.f,0.f};
#pragma unroll
  for (int kt = 0; kt < 4; ++kt) {
    int s = kt * 4 + g;
    bf16x8 a = *(const bf16x8*)&Qls[l16][(s ^ l16) * 4];
#pragma unroll
    for (int n = 0; n < 2; ++n) {
      int nt = wv * 2 + n;
      bf16x8 b = *(const bf16x8*)(Wtp + (size_t)(nt * 16 + l16) * DW + kt * 16 + g * 4);
      acc[n] = __builtin_amdgcn_mfma_f32_16x16x32_bf16(a, b, acc[n], 0, 0, 0);
    }
  }
#pragma unroll
  for (int r = 0; r < 4; ++r) {
    int lrow = g * 4 + r;
    int erow = blockIdx.x * 16 + lrow;
    float s = ivls[lrow], qq = qls[lrow];
#pragma unroll
    for (int n = 0; n < 2; ++n) {
      int cc = (wv * 2 + n) * 16 + l16;
      float val = s * (acc[n][r] + qq * bias[cc]);
      unsigned int u = __float_as_uint(val);
      u = (u + 0x7FFFu + ((u >> 16) & 1u)) >> 16;
      Yeb[(size_t)erow * D + cc] = (unsigned short)u;
    }
  }
}

// ---------------- fallback: fused gather+GEMM (ws too small for Qp) ----------------
__global__ __launch_bounds__(256) void k_eg_gemm(const unsigned int* __restrict__ Xs, const float* __restrict__ risv,
                                                 const int* __restrict__ starts_e, const int* __restrict__ cnt_e,
                                                 const unsigned int* __restrict__ members,
                                                 const unsigned int* __restrict__ Wtp, const float* __restrict__ bias,
                                                 const float* __restrict__ invde, unsigned short* __restrict__ Yeb) {
  __shared__ unsigned int Qls[16][DW];
  __shared__ float qls[16], ivls[16];
  int tid = threadIdx.x;
  int wv = tid >> 6, lane = tid & 63;
  int g = lane >> 4, l16 = lane & 15;
  int row = wv * 4 + g;
  int e = blockIdx.x * 16 + row;
  int beg = starts_e[e];
  int cnt = cnt_e[e];
  int maxc = cnt;
  maxc = max(maxc, __shfl_xor(maxc, 16));
  maxc = max(maxc, __shfl_xor(maxc, 32));
  float a0=0,a1=0,a2=0,a3=0,a4=0,a5=0,a6=0,a7=0,q=0.f;
  for (int i = 0; i < maxc; i += 8) {
    int vv[8];
#pragma unroll
    for (int j = 0; j < 8; ++j) {
      int idx = i + j;
      int m = (int)members[beg + idx];
      vv[j] = (idx < cnt) ? m : N_NODES;
    }
    uint4 xx[8];
#pragma unroll
    for (int j = 0; j < 8; ++j) xx[j] = *(const uint4*)(Xs + (size_t)vv[j] * DW + l16 * 4);
#pragma unroll
    for (int j = 0; j < 8; ++j) q += risv[vv[j]];
#pragma unroll
    for (int j = 0; j < 8; ++j) {
      a0 += __uint_as_float(xx[j].x << 16); a1 += __uint_as_float(xx[j].x & 0xFFFF0000u);
      a2 += __uint_as_float(xx[j].y << 16); a3 += __uint_as_float(xx[j].y & 0xFFFF0000u);
      a4 += __uint_as_float(xx[j].z << 16); a5 += __uint_as_float(xx[j].z & 0xFFFF0000u);
      a6 += __uint_as_float(xx[j].w << 16); a7 += __uint_as_float(xx[j].w & 0xFFFF0000u);
    }
  }
  uint4 o;
  o.x = pack_bf2(a0, a1); o.y = pack_bf2(a2, a3);
  o.z = pack_bf2(a4, a5); o.w = pack_bf2(a6, a7);
  *(uint4*)&Qls[row][(l16 ^ row) * 4] = o;
  if (l16 == 0) { qls[row] = q; ivls[row] = invde[e]; }
  __syncthreads();
  f32x4 acc[2];
  acc[0] = (f32x4){0.f,0.f,0.f,0.f}; acc[1] = (f32x4){0.f,0.f,0.f,0.f};
#pragma unroll
  for (int kt = 0; kt < 4; ++kt) {
    int s = kt * 4 + g;
    bf16x8 a = *(const bf16x8*)&Qls[l16][(s ^ l16) * 4];
#pragma unroll
    for (int n = 0; n < 2; ++n) {
      int nt = wv * 2 + n;
      bf16x8 b = *(const bf16x8*)(Wtp + (size_t)(nt * 16 + l16) * DW + kt * 16 + g * 4);
      acc[n] = __builtin_amdgcn_mfma_f32_16x16x32_bf16(a, b, acc[n], 0, 0, 0);
    }
  }
#pragma unroll
  for (int r = 0; r < 4; ++r) {
    int lrow = g * 4 + r;
    int erow = blockIdx.x * 16 + lrow;
    float s = ivls[lrow], qq = qls[lrow];
#pragma unroll
    for (int n = 0; n < 2; ++n) {
      int cc = (wv * 2 + n) * 16 + l16;
      float val = s * (acc[n][r] + qq * bias[cc]);
      unsigned int u = __float_as_uint(val);
      u = (u + 0x7FFFu + ((u >> 16) & 1u)) >> 16;
      Yeb[(size_t)erow * D + cc] = (unsigned short)u;
    }
  }
}

// ---------------- phase B: 4 vertices per wave, 16 lanes x uint4 per row ----------------
__global__ __launch_bounds__(256) void k_vertex_gather(const unsigned int* __restrict__ Yeb, const float* __restrict__ risv,
                                const int* __restrict__ starts_v, const int* __restrict__ cnt_v,
                                const unsigned int* __restrict__ members,
                                float* __restrict__ out) {
  int wv = (blockIdx.x * 256 + threadIdx.x) >> 6;
  int lane = threadIdx.x & 63;
  int g = lane >> 4, l16 = lane & 15;
  int v = wv * 4 + g;
  if (v >= N_NODES) return;
  int beg = starts_v[v];
  int cnt = cnt_v[v];
  int maxc = cnt;
  maxc = max(maxc, __shfl_xor(maxc, 16));
  maxc = max(maxc, __shfl_xor(maxc, 32));
  float a0=0,a1=0,a2=0,a3=0,a4=0,a5=0,a6=0,a7=0;
  for (int i = 0; i < maxc; i += 8) {
    int ee[8];
#pragma unroll
    for (int j = 0; j < 8; ++j) {
      int idx = i + j;
      int m = (int)members[beg + idx];
      ee[j] = (idx < cnt) ? m : N_EDGES;
    }
    uint4 yy[8];
#pragma unroll
    for (int j = 0; j < 8; ++j) yy[j] = *(const uint4*)(Yeb + (size_t)ee[j] * DW + l16 * 4);
#pragma unroll
    for (int j = 0; j < 8; ++j) {
      a0 += __uint_as_float(yy[j].x << 16); a1 += __uint_as_float(yy[j].x & 0xFFFF0000u);
      a2 += __uint_as_float(yy[j].y << 16); a3 += __uint_as_float(yy[j].y & 0xFFFF0000u);
      a4 += __uint_as_float(yy[j].z << 16); a5 += __uint_as_float(yy[j].z & 0xFFFF0000u);
      a6 += __uint_as_float(yy[j].w << 16); a7 += __uint_as_float(yy[j].w & 0xFFFF0000u);
    }
  }
  float s = risv[v];
  float4 o0, o1;
  o0.x = fmaxf(a0 * s, 0.f); o0.y = fmaxf(a1 * s, 0.f);
  o0.z = fmaxf(a2 * s, 0.f); o0.w = fmaxf(a3 * s, 0.f);
  o1.x = fmaxf(a4 * s, 0.f); o1.y = fmaxf(a5 * s, 0.f);
  o1.z = fmaxf(a6 * s, 0.f); o1.w = fmaxf(a7 * s, 0.f);
  float* orow = out + (size_t)v * D + l16 * 8;
  *(float4*)orow = o0;
  *(float4*)(orow + 4) = o1;
}

extern "C" void kernel_launch(void* const* d_in, const int* in_sizes, int n_in,
                              void* d_out, int out_size, void* d_ws, size_t ws_size,
                              hipStream_t stream) {
  const float* X    = (const float*)d_in[0];
  const float* W    = (const float*)d_in[1];
  const float* bias = (const float*)d_in[2];
  const int* v_idx  = (const int*)d_in[3];
  const int* e_idx  = (const int*)d_in[4];
  float* out = (float*)d_out;

  char* p = (char*)d_ws;
  auto alloc = [&](size_t bytes) { char* r = p; p += (bytes + 255) & ~(size_t)255; return r; };
  unsigned int* Te  = (unsigned int*)alloc(((size_t)NB + 1) * CAP_E * 4);   // +1 bucket slack pad
  unsigned int* Tv  = (unsigned int*)alloc(((size_t)NB + 1) * CAP_V * 4);
  unsigned int* Xs  = (unsigned int*)alloc((size_t)(N_NODES + 1) * DW * 4);
  unsigned int* Yeb = (unsigned int*)alloc((size_t)(N_EDGES + 1) * DW * 4);
  unsigned int* Wtp = (unsigned int*)alloc((size_t)D * DW * 4);
  float* risv  = (float*)alloc((size_t)(N_NODES + 1) * 4);
  float* invde = (float*)alloc((size_t)N_EDGES * 4);
  int* cnt_e    = (int*)alloc((size_t)N_EDGES * 4);
  uint2* cnt_es = (uint2*)alloc((size_t)N_EDGES * 8);
  int* cnt_v    = (int*)alloc((size_t)N_NODES * 4);
  int* starts_e = (int*)alloc((size_t)N_EDGES * 4);
  int* starts_v = (int*)alloc((size_t)N_NODES * 4);
  int* cursors  = (int*)alloc((size_t)2 * NB * 4);
  int* ce = cursors, *cv = cursors + NB;
  // sliced-path scratch last, gated on ws_size
  unsigned int* Qp = (unsigned int*)alloc((size_t)N_EDGES * NSLICE * DW * 4);  // 41 MB
  float* qp        = (float*)alloc((size_t)N_EDGES * NSLICE * 4);
  size_t need = (size_t)(p - (char*)d_ws);
  bool sliced = ws_size >= need;

  k_zero_cursors<<<1, 2 * NB, 0, stream>>>(cursors);
  k_bin<<<P1_BLOCKS, 256, 0, stream>>>(v_idx, e_idx, ce, cv, Te, Tv);
  k_sort<<<2 * NB + 32, 256, 0, stream>>>(ce, cv, Te, Tv, cnt_e, invde, starts_e, cnt_es,
                                          cnt_v, risv, starts_v, X, Xs, W, Wtp, Yeb);
  if (sliced) {
    k_egA<<<NSLICE * (N_EDGES / 16), 256, 0, stream>>>(Xs, risv, starts_e, cnt_es, Te, Qp, qp);
    k_gemm2<<<N_EDGES / 16, 256, 0, stream>>>(Qp, qp, Wtp, bias, invde, (unsigned short*)Yeb);
  } else {
    k_eg_gemm<<<N_EDGES / 16, 256, 0, stream>>>(Xs, risv, starts_e, cnt_e, Te, Wtp, bias, invde,
                                                (unsigned short*)Yeb);
  }
  k_vertex_gather<<<(N_NODES / 4 + 3) / 4, 256, 0, stream>>>(Yeb, risv, starts_v, cnt_v, Tv, out);
}